// Round 3
// baseline (12229.402 us; speedup 1.0000x reference)
//
#include <hip/hip_runtime.h>
#include <math.h>

#define DEV static __device__ __forceinline__

typedef int v4i __attribute__((ext_vector_type(4)));
typedef float v4f __attribute__((ext_vector_type(4)));
typedef __bf16 bf16_t;
typedef __bf16 v8bf __attribute__((ext_vector_type(8)));

// ---------------- calibration (s, z) constants, computed like the reference ----------------
struct SZ { float s, z; };

constexpr double cfloor_(double v){ long long i=(long long)v; return ((double)i > v) ? (double)(i-1) : (double)i; }
constexpr double cround_(double v){            // round half-to-even (Python round / nearbyint)
  double fl = cfloor_(v); double fr = v - fl;
  return (fr > 0.5) ? fl + 1.0 : (fr < 0.5 ? fl : ((((long long)fl) & 1LL) == 0 ? fl : fl + 1.0));
}
constexpr SZ mksz(double mn, double mx){
  double s = (mx - mn) / 255.0;
  double z = cround_(-mn / s);
  return SZ{ (float)s, (float)z };
}

constexpr SZ Zx     = mksz(-0.0025095, 0.0022181);
constexpr SZ ZW1    = mksz(-0.22075387835502625, 0.208940327167511);
constexpr SZ Zfc1mm = mksz(-0.00291599917, 0.0017367251);
constexpr SZ Zbfc1  = mksz(-0.48688140511512756, 0.5176185369491577);
constexpr SZ Zfc1add= mksz(-0.48778465390205383, 0.5181604027748108);
// layer-1 weights/biases
constexpr SZ ZWiz1 = mksz(-0.43284985423088074, 0.46175122261047363);
constexpr SZ ZWir1 = mksz(-0.34401071071624756, 0.29191476106643677);
constexpr SZ ZWin1 = mksz(-0.3236880302429199, 0.39607325196266174);
constexpr SZ ZWhz1 = mksz(-1.8417714834213257, 1.7173254489898682);
constexpr SZ ZWhr1 = mksz(-1.1574513912200928, 1.0300449132919312);
constexpr SZ ZWhn1 = mksz(-0.7756922245025635, 0.9530389308929443);
constexpr SZ Zbiz1 = mksz(-0.5063393712043762, 0.36664387583732605);
constexpr SZ Zbir1 = mksz(-0.07920225709676743, 0.20611026883125305);
constexpr SZ Zbin1 = mksz(-0.5539973378181458, 0.17938342690467834);
constexpr SZ Zbhz1 = mksz(-0.5337516665458679, 0.4148772358894348);
constexpr SZ Zbhr1 = mksz(-0.07688436657190323, 0.14814253151416779);
constexpr SZ Zbhn1 = mksz(-0.7828555107116699, 0.9008108973503113);
// layer-2 weights/biases
constexpr SZ ZWiz2 = mksz(-0.9102030992507935, 0.9408696889877319);
constexpr SZ ZWir2 = mksz(-0.9560997486114502, 0.6683358550071716);
constexpr SZ ZWin2 = mksz(-0.4721935987472534, 0.48561596870422363);
constexpr SZ ZWhz2 = mksz(-1.2992678880691528, 1.2991048097610474);
constexpr SZ ZWhr2 = mksz(-0.8318714499473572, 1.1085889339447021);
constexpr SZ ZWhn2 = mksz(-0.955470085144043, 1.046797513961792);
constexpr SZ Zbiz2 = mksz(-0.44805487990379333, 0.1560053527355194);
constexpr SZ Zbir2 = mksz(-0.08767592161893845, 0.11347303539514542);
constexpr SZ Zbin2 = mksz(-0.239909827709198, 0.12033259868621826);
constexpr SZ Zbhz2 = mksz(-0.43745461106300354, 0.12699371576309204);
constexpr SZ Zbhr2 = mksz(-0.09617264568805695, 0.07690174877643585);
constexpr SZ Zbhn2 = mksz(-0.17204178869724274, 0.19739042222499847);
// fc tail
constexpr SZ ZWfc2 = mksz(-1.3657219409942627, 1.158295750617981);
constexpr SZ Zbfc2 = mksz(-0.1750922054052353, 0.1385071724653244);
constexpr SZ ZWfc3 = mksz(-3.1666038036346436, 2.5026357173919678);
constexpr SZ Zbfc3 = mksz(-0.10188056528568268, 0.0899151861667633);
constexpr SZ ZWfc4 = mksz(-1.300571084022522, 1.928941249847412);
constexpr SZ Zbfc4 = mksz(-0.10699586570262909, 0.04597663879394531);
// gru1 stages
constexpr SZ Za_1 = mksz(-0.6389939785003662, 0.7715625762939453);
constexpr SZ Za1  = mksz(-0.6046768426895142, 0.8871182203292847);
constexpr SZ Zb_1 = mksz(-0.004922409541904926, 0.004103424027562141);
constexpr SZ Zb1  = mksz(-0.07475128024816513, 0.14630259573459625);
constexpr SZ Zc_1 = mksz(-1.5660111904144287, 1.0454494953155518);
constexpr SZ Zc1  = mksz(-1.9779117107391357, 1.3700535297393799);
constexpr SZ Zd_1 = mksz(-0.008429044857621193, 0.006403823848813772);
constexpr SZ Zd1  = mksz(-0.5529640316963196, 0.41507571935653687);
constexpr SZ Ze_1 = mksz(-1.3637111186981201, 1.018247127532959);
constexpr SZ Ze1  = mksz(-1.8583884239196777, 1.1587692499160767);
constexpr SZ Zf_1 = mksz(-0.005411399528384209, 0.0061536869034171104);
constexpr SZ Zf1  = mksz(-0.7833794355392456, 0.8978855013847351);
constexpr SZ Zr_1 = mksz(-0.6226556301116943, 0.9800534844398499);
constexpr SZ Zr1  = mksz(0.3491777181625366, 0.7271188497543335);
constexpr SZ Zz_1 = mksz(-2.392332077026367, 1.7851293087005615);
constexpr SZ Zz1  = mksz(0.08375928550958633, 0.856329083442688);
constexpr SZ Zn11 = mksz(-0.5516456365585327, 0.4556601643562317);
constexpr SZ Zn21 = mksz(-2.4100341796875, 1.1423156261444092);
constexpr SZ Zn1  = mksz(-0.983996570110321, 0.8151924014091492);
constexpr SZ Zhn11= mksz(0.143670916557312, 0.9162406921386719);
constexpr SZ Zhn21= mksz(-0.9015777111053467, 0.45391541719436646);
constexpr SZ Zhn31= mksz(-0.0016954239690676332, 0.0016671211924403906);
constexpr SZ Zrnn = mksz(-0.9016271829605103, 0.4546271562576294);
// gru2 explicit entries (the rest fall back to gru1 values, incl. rnn2GRU)
constexpr SZ Za_2 = mksz(-0.681461751461029, 0.9113116264343262);
constexpr SZ Za2  = mksz(-0.7149235010147095, 0.908741295337677);
constexpr SZ Zb_2 = mksz(-0.005148397758603096, 0.011014967225492);
constexpr SZ Zb2g = mksz(-0.09436552226543427, 0.07623167335987091);
constexpr SZ Zc_2 = mksz(-1.2279887199401855, 1.1102137565612793);
constexpr SZ Zc2  = mksz(-1.6760436296463013, 1.200895071029663);
constexpr SZ Zd_2 = mksz(-0.008141756057739258, 0.00894666276872158);
constexpr SZ Zd2  = mksz(-0.43875735998153687, 0.1262134611606598);
constexpr SZ Ze_2 = mksz(-0.6732944250106812, 0.6314664483070374);

struct RecP {
  SZ wr, wz, wn;
  SZ a, c, e;
  SZ b1, b2, d1, d2, f1, f2;
  SZ r1, r2, z1, z2;
  SZ n1, n2, n3;
  SZ hn1, hn2, hn3, rnn;
};
constexpr RecP PL1 = { ZWhr1, ZWhz1, ZWhn1, Za1, Zc1, Ze1, Zb_1, Zb1, Zd_1, Zd1, Zf_1, Zf1,
                       Zr_1, Zr1, Zz_1, Zz1, Zn11, Zn21, Zn1, Zhn11, Zhn21, Zhn31, Zrnn };
constexpr RecP PL2 = { ZWhr2, ZWhz2, ZWhn2, Za2, Zc2, Ze1, Zb_2, Zb2g, Zd_2, Zd2, Zf_1, Zf1,
                       Zr_1, Zr1, Zz_1, Zz1, Zn11, Zn21, Zn1, Zhn11, Zhn21, Zhn31, Zrnn };

// ---------------- device helpers ----------------
DEV float fq_(float x, float s, float z){
  float q = rintf(x / s) + z;
  q = fminf(fmaxf(q, 0.f), 255.f);
  return (q - z) * s;
}
DEV float sigm_(float v){ return 1.f / (1.f + expf(-v)); }

DEV unsigned udot4_(unsigned a, unsigned b, unsigned c){
#if defined(__has_builtin) && __has_builtin(__builtin_amdgcn_udot4)
  return __builtin_amdgcn_udot4(a, b, c, false);
#else
  return c + (a & 255u) * (b & 255u) + ((a >> 8) & 255u) * ((b >> 8) & 255u)
           + ((a >> 16) & 255u) * ((b >> 16) & 255u) + (a >> 24) * (b >> 24);
#endif
}

// ---------------- prep kernels ----------------
struct BJob { const float* src; float* dst; int n; float s; float z; };
struct BJobs { BJob j[16]; };
__global__ __launch_bounds__(256) void kbias(BJobs jobs){
  BJob J = jobs.j[blockIdx.x];
  for (int i = threadIdx.x; i < J.n; i += 256) J.dst[i] = fq_(J.src[i], J.s, J.z);
}

struct W6 { const float* W[6]; float s[6]; float z[6]; };
// six Wh [400][400] (k-major) -> u8 codes, column-major [m][j][k]
__global__ __launch_bounds__(256) void kwhc6(W6 jb, unsigned char* __restrict__ dst){
  int i = blockIdx.x * 256 + threadIdx.x;
  if (i < 960000) {
    int m = i / 160000, r = i - m * 160000;
    int j = r / 400, k = r - j * 400;
    float q = rintf(jb.W[m][k * 400 + j] / jb.s[m]) + jb.z[m];
    q = fminf(fmaxf(q, 0.f), 255.f);
    dst[i] = (unsigned char)q;
  }
}
__global__ __launch_bounds__(256) void kcolsum(const unsigned char* __restrict__ WhC, int* __restrict__ cs){
  int i = blockIdx.x * 256 + threadIdx.x;
  if (i < 2400) {
    const unsigned char* p = WhC + (size_t)i * 400;
    int s = 0;
    for (int k = 0; k < 400; ++k) s += p[k];
    cs[i] = s;
  }
}
// six Wi [400][400] -> transposed biased codes [m][n][464] + colsum(q-128)
__global__ __launch_bounds__(256) void kwic6(W6 jb, signed char* __restrict__ WiT, int* __restrict__ cs){
  for (int idx = blockIdx.x * 256 + threadIdx.x; idx < 960000; idx += gridDim.x * 256) {
    int m = idx / 160000, r = idx - m * 160000;
    int k = r / 400, n = r - k * 400;
    float q = rintf(jb.W[m][r] / jb.s[m]) + jb.z[m];
    q = fminf(fmaxf(q, 0.f), 255.f);
    int qi = (int)q;
    WiT[(size_t)m * 185600 + (size_t)n * 464 + k] = (signed char)(qi ^ 0x80);
    atomicAdd(&cs[m * 400 + n], qi - 128);
  }
  for (int idx = blockIdx.x * 256 + threadIdx.x; idx < 153600; idx += gridDim.x * 256) {
    int m = idx / 25600, r = idx - m * 25600;
    int n = r / 64, p = r - n * 64;
    WiT[(size_t)m * 185600 + (size_t)n * 464 + 400 + p] = 0;
  }
}
// W [K][N] f32 -> transposed biased codes Bt [N][464] + colsum(q-128)  (FC1/FC2)
__global__ __launch_bounds__(256) void kwic(const float* __restrict__ W, signed char* __restrict__ Bt,
                                            int* __restrict__ cs, float s, float z, int K, int N){
  int total1 = K * N, total2 = (464 - K) * N;
  for (int idx = blockIdx.x * 256 + threadIdx.x; idx < total1; idx += gridDim.x * 256) {
    int k = idx / N, n = idx - k * N;
    float q = rintf(W[idx] / s) + z;
    q = fminf(fmaxf(q, 0.f), 255.f);
    int qi = (int)q;
    Bt[(size_t)n * 464 + k] = (signed char)(qi ^ 0x80);
    atomicAdd(&cs[n], qi - 128);
  }
  for (int idx = blockIdx.x * 256 + threadIdx.x; idx < total2; idx += gridDim.x * 256) {
    int n = idx / (464 - K), k = K + (idx - n * (464 - K));
    Bt[(size_t)n * 464 + k] = 0;
  }
}
// W [K][N] f32 -> transposed bf16 INTEGER codes (q-z) in [N][608] (pad 0)  (FC3/FC4)
__global__ __launch_bounds__(256) void kwbf(const float* __restrict__ W, bf16_t* __restrict__ Bt,
                                            float s, float z, int K, int N){
  int total1 = K * N, total2 = (608 - K) * N;
  for (int idx = blockIdx.x * 256 + threadIdx.x; idx < total1; idx += gridDim.x * 256) {
    int k = idx / N, n = idx - k * N;
    float q = rintf(W[idx] / s) + z;
    q = fminf(fmaxf(q, 0.f), 255.f);
    Bt[(size_t)n * 608 + k] = (bf16_t)(q - z);     // integer in [-255,255]: exact in bf16
  }
  for (int idx = blockIdx.x * 256 + threadIdx.x; idx < total2; idx += gridDim.x * 256) {
    int n = idx / (608 - K), k = K + (idx - n * (608 - K));
    Bt[(size_t)n * 608 + k] = (bf16_t)0.f;
  }
}
// quantize x [B,T,F] -> xcq codes [T*64+b][464] (pads = code 128)
__global__ __launch_bounds__(256) void kxq(const float* __restrict__ x, unsigned char* __restrict__ xcq,
                                           float s, float z){
  int idx = blockIdx.x * 256 + threadIdx.x;
  if (idx < 64000 * 464) {
    int row = idx / 464, c = idx - row * 464;
    unsigned char code = 128;
    if (c < 257) {
      int bb = row & 63, tt = row >> 6;
      float q = rintf(x[((size_t)bb * 1000 + tt) * 257 + c] / s) + z;
      q = fminf(fmaxf(q, 0.f), 255.f);
      code = (unsigned char)q;
    }
    xcq[idx] = code;
  }
}
// per-row sums of (q-128) over w4 uint4-words of u8 codes (pads must be code 128)
__global__ __launch_bounds__(256) void krsum(const unsigned char* __restrict__ A, int* __restrict__ rs,
                                             int w4){
  int r = blockIdx.x * 256 + threadIdx.x;
  const unsigned* p = (const unsigned*)(A + (size_t)r * (w4 * 16));
  unsigned s = 0;
  for (int i = 0; i < w4 * 4; ++i) s = udot4_(p[i], 0x01010101u, s);
  rs[r] = (int)s - 128 * 4 * (w4 * 4);
}

// ---------------- exact-int i8 MFMA GEMM ----------------
// BM=64, BN=80, K padded to 448. dot_int = S + czw*RA' + cza*CW' + cconst.
__global__ __launch_bounds__(256) void gemm_i8(
    const unsigned char* __restrict__ Au8, int strideA, int aw4,
    const int* __restrict__ rowsum,
    const signed char* __restrict__ Bt, const int* __restrict__ colsum,
    const float* __restrict__ bias,
    unsigned char* __restrict__ outU8, float* __restrict__ outF,
    int N, int nb, int outStride, int epMode,
    int czw, int cza, int cconst, float ss,
    float e1S, float e1Z, float e2S, float e2Z)
{
  __shared__ __align__(16) signed char Asl[64 * 464];
  __shared__ __align__(16) signed char Bsl[80 * 464];
  const int tid = threadIdx.x;
  const int bm = blockIdx.x / nb;
  const int bn = blockIdx.x - bm * nb;
  const int m0 = bm * 64;
  const int n0 = bn * 80;
  for (int i = tid; i < 80 * 29; i += 256) {
    int r = i / 29, c = i - r * 29;
    uint4 v;
    if (n0 + r < N) v = *(const uint4*)(Bt + (size_t)(n0 + r) * 464 + c * 16);
    else { v.x = 0u; v.y = 0u; v.z = 0u; v.w = 0u; }
    *(uint4*)(Bsl + (size_t)r * 464 + c * 16) = v;
  }
  for (int i = tid; i < 64 * 29; i += 256) {
    int r = i / 29, c = i - r * 29;
    uint4 v;
    if (c < aw4) {
      v = *(const uint4*)(Au8 + (size_t)(m0 + r) * strideA + c * 16);
      v.x ^= 0x80808080u; v.y ^= 0x80808080u; v.z ^= 0x80808080u; v.w ^= 0x80808080u;
    } else { v.x = 0u; v.y = 0u; v.z = 0u; v.w = 0u; }
    *(uint4*)(Asl + (size_t)r * 464 + c * 16) = v;
  }
  __syncthreads();
  const int wv = tid >> 6, ln = tid & 63;
  const int lr = ln & 15;
  const int lk = ln >> 4;
  v4i acc[5];
#pragma unroll
  for (int j = 0; j < 5; ++j) { acc[j][0] = 0; acc[j][1] = 0; acc[j][2] = 0; acc[j][3] = 0; }
#pragma unroll
  for (int kc = 0; kc < 7; ++kc) {
    int kb = kc * 64 + lk * 16;
    v4i a = *(const v4i*)(Asl + (size_t)(wv * 16 + lr) * 464 + kb);
#pragma unroll
    for (int j = 0; j < 5; ++j) {
      v4i b = *(const v4i*)(Bsl + (size_t)(j * 16 + lr) * 464 + kb);
      acc[j] = __builtin_amdgcn_mfma_i32_16x16x64_i8(a, b, acc[j], 0, 0, 0);
    }
  }
#pragma unroll
  for (int reg = 0; reg < 4; ++reg) {
    int row = m0 + wv * 16 + lk * 4 + reg;
    int RA = rowsum[row];
#pragma unroll
    for (int j = 0; j < 5; ++j) {
      int col = n0 + j * 16 + lr;
      if (col >= N) continue;
      int I = acc[j][reg] + czw * RA + cza * colsum[col] + cconst;
      float v = (float)I * ss;
      if (epMode == 0) {
        v = fq_(v, e1S, e1Z) + bias[col];
        float q = rintf(v / e2S) + e2Z;
        q = fminf(fmaxf(q, 0.f), 255.f);
        outU8[(size_t)row * outStride + col] = (unsigned char)q;
      } else {
        v += bias[col];
        v = fmaxf(v, 0.f);
        outF[(size_t)row * outStride + col] = v;
      }
    }
  }
}

// ---------------- bf16x2-split MFMA GEMM (FC3/FC4) ----------------
__global__ __launch_bounds__(512) void gemm_bf(
    const float* __restrict__ A, const bf16_t* __restrict__ Bt,
    const float* __restrict__ bias, float* __restrict__ outF,
    int N, int nb, int epMode, int rowOff, float sc)
{
  __shared__ __align__(16) bf16_t Bs[128 * 616];   // row stride 616 (conflict-free b128)
  const int tid = threadIdx.x;
  const int bm = blockIdx.x / nb;
  const int bn = blockIdx.x - bm * nb;
  const int m0 = bm * 128;
  const int n0 = bn * 128;
  for (int i = tid; i < 128 * 76; i += 512) {
    int r = i / 76, c = i - r * 76;
    uint4 v; v.x = 0u; v.y = 0u; v.z = 0u; v.w = 0u;
    if (n0 + r < N) v = *(const uint4*)((const char*)(Bt + (size_t)(n0 + r) * 608) + c * 16);
    *(uint4*)((char*)(Bs + (size_t)r * 616) + c * 16) = v;
  }
  __syncthreads();
  const int wv = tid >> 6, ln = tid & 63;
  const int lr = ln & 15, quad = ln >> 4;
  const float* arp = A + (size_t)(m0 + wv * 16 + lr) * 600;
  v4f acc[8];
#pragma unroll
  for (int j = 0; j < 8; ++j) { acc[j][0] = 0.f; acc[j][1] = 0.f; acc[j][2] = 0.f; acc[j][3] = 0.f; }
  for (int kc = 0; kc < 19; ++kc) {
    int kb = kc * 32 + quad * 8;
    float af[8];
    if (kc == 18 && quad == 3) {
#pragma unroll
      for (int j = 0; j < 8; ++j) af[j] = 0.f;
    } else {
      *(float4*)&af[0] = *(const float4*)(arp + kb);
      *(float4*)&af[4] = *(const float4*)(arp + kb + 4);
    }
    v8bf ah, al;
#pragma unroll
    for (int j = 0; j < 8; ++j) {
      float xx = af[j];
      bf16_t h = (bf16_t)xx;
      ah[j] = h;
      al[j] = (bf16_t)(xx - (float)h);
    }
#pragma unroll
    for (int nf = 0; nf < 8; ++nf) {
      v8bf bfrag = *(const v8bf*)(Bs + (size_t)(nf * 16 + lr) * 616 + kc * 32 + quad * 8);
      acc[nf] = __builtin_amdgcn_mfma_f32_16x16x32_bf16(ah, bfrag, acc[nf], 0, 0, 0);
      acc[nf] = __builtin_amdgcn_mfma_f32_16x16x32_bf16(al, bfrag, acc[nf], 0, 0, 0);
    }
  }
#pragma unroll
  for (int nf = 0; nf < 8; ++nf) {
    int col = n0 + nf * 16 + lr;
    if (col >= N) continue;
    float bcol = bias[col];
#pragma unroll
    for (int reg = 0; reg < 4; ++reg) {
      int row = m0 + wv * 16 + quad * 4 + reg;
      float v = acc[nf][reg] * sc + bcol;
      if (epMode == 2) {
        v = fmaxf(v, 0.f);
        outF[(size_t)row * N + col] = v;
      } else {
        v = sigm_(v);
        int rg = rowOff + row;
        int tt = rg >> 6, bb = rg & 63;
        outF[((size_t)bb * 1000 + tt) * 257 + col] = v;
      }
    }
  }
}

// ---------------- GRU recurrence: one block per batch, weights in VGPRs+LDS ----------------
// 64 blocks x 512 threads (8 waves). amdgpu_waves_per_eu(2,2) pins BOTH min and max
// occupancy to 2 waves/SIMD -> 256-VGPR budget the RA must actually use (launch_bounds'
// 2nd arg alone is only a lower bound on occupancy; R2 showed the heuristic still
// targeted 4 waves/EU and spilled wq at VGPR_Count=128).
// 1200 dots x 4 k-quarters = 4800 quarter-slots. Slot q = tid + 512*s:
// s=0..7 in REGISTERS (wq[8][25] = 200 VGPRs), s=8 (all tid) and s=9 (tid<192) in LDS.
// part (q&3) == (tid&3) for all slots -> fixed 25-word h slice per thread; quad lanes
// hold the 4 parts of each dot -> 2x shfl_xor butterfly completes dots. Zero-point
// corrections applied in elementwise phase via ic_l[d] = -zh*colsum[d] + 400*zh*zw(g).
__global__ __launch_bounds__(512)
__attribute__((amdgpu_waves_per_eu(2, 2)))
void gru_rec512(
    const unsigned char* __restrict__ WhC, const int* __restrict__ colsum,
    const unsigned char* __restrict__ Aq, const unsigned char* __restrict__ Cq,
    const unsigned char* __restrict__ Eq,
    const float* __restrict__ bhr, const float* __restrict__ bhz, const float* __restrict__ bhn,
    unsigned char* __restrict__ hs, RecP P)
{
  __shared__ __align__(16) unsigned Wl[704 * 28];   // 78,848 B: LDS quarter-slots (stride 28)
  __shared__ __align__(16) unsigned hq[2][4 * 28];  // h codes, [part][25 words] stride 28
  __shared__ int dots_i[1200];                      // raw integer dots
  __shared__ unsigned acew[2][300];                 // a/c/e codes for step t
  __shared__ int ic_l[1200];                        // per-dot integer correction
  __shared__ float bias_l[1200];                    // fq'd bh biases per dot
  __shared__ int HqS[2];                            // sum of h codes

  const int tid = threadIdx.x;
  const int b = blockIdx.x;
  const unsigned* Wu = (const unsigned*)WhC;

  // ---- register-resident weight quarters (8 x 25 dwords = 200 VGPRs) ----
  unsigned wq[8][25];
#pragma unroll
  for (int s = 0; s < 8; ++s) {
    int q = tid + 512 * s;
    const unsigned* src = Wu + (q >> 2) * 100 + (q & 3) * 25;
#pragma unroll
    for (int w = 0; w < 25; ++w) wq[s][w] = src[w];
  }
  // ---- LDS weight quarters: q in [4096, 4800) ----
  for (int i = tid; i < 704 * 25; i += 512) {
    int ql = i / 25, w = i - ql * 25;
    int q = 4096 + ql;
    Wl[ql * 28 + w] = Wu[(q >> 2) * 100 + (q & 3) * 25 + w];
  }
  // ---- per-dot correction + bias tables ----
  const int zh = (int)P.rnn.z;
  for (int d = tid; d < 1200; d += 512) {
    int g = (d >= 800) ? 2 : (d >= 400 ? 1 : 0);
    int zw = (g == 0) ? (int)P.wr.z : (g == 1) ? (int)P.wz.z : (int)P.wn.z;
    ic_l[d] = -zh * colsum[d] + 400 * zh * zw;
    int j = d - g * 400;
    bias_l[d] = ((g == 0) ? bhr : (g == 1) ? bhz : bhn)[j];
  }
  // ---- h0 / HqS / ace(t=0) init ----
  const unsigned code0 = (unsigned)fminf(fmaxf(P.rnn.z, 0.f), 255.f);
  for (int i = tid; i < 100; i += 512)
    hq[0][(i / 25) * 28 + (i % 25)] = code0 * 0x01010101u;
  if (tid == 0) { HqS[0] = 400 * (int)code0; HqS[1] = 0; }
  const unsigned char* psrc = nullptr;
  int poff = 0;
  if (tid < 300) {
    int g = tid / 100, w = tid - g * 100;
    psrc = (g == 0) ? Aq : (g == 1) ? Cq : Eq;
    poff = w * 4;
    acew[0][tid] = *(const unsigned*)(psrc + (size_t)b * 400 + poff);
  }
  __syncthreads();

  const int part = tid & 3;
  const int grp = tid >> 2;
  const unsigned* hbase0 = &hq[0][part * 28];
  const unsigned* hbase1 = &hq[1][part * 28];
  const unsigned* wl8 = &Wl[tid * 28];
  const unsigned* wl9 = &Wl[(512 + tid) * 28];   // used only for tid<192
  const int zwr = (int)P.wr.z, zwz = (int)P.wz.z, zwn = (int)P.wn.z;
  const float swr = P.wr.s * P.rnn.s, swz = P.wz.s * P.rnn.s, swn = P.wn.s * P.rnn.s;

  unsigned pf = 0;
  unsigned hcode = code0;

  for (int t = 0; t < 1000; ++t) {
    // ---------------- phase D: dots ----------------
    if (tid < 300) {
      int tn = (t + 1 < 1000) ? (t + 1) : 999;
      pf = *(const unsigned*)(psrc + ((size_t)tn * 64 + b) * 400 + poff);
    }
    if (tid == 511) HqS[(t + 1) & 1] = 0;
    const unsigned* hb = (t & 1) ? hbase1 : hbase0;
    unsigned a[10];
#pragma unroll
    for (int s = 0; s < 10; ++s) a[s] = 0u;
#pragma unroll
    for (int c = 0; c < 6; ++c) {
      uint4 h4 = *(const uint4*)(hb + 4 * c);
#pragma unroll
      for (int s = 0; s < 8; ++s) {
        a[s] = udot4_(wq[s][4*c+0], h4.x, a[s]);
        a[s] = udot4_(wq[s][4*c+1], h4.y, a[s]);
        a[s] = udot4_(wq[s][4*c+2], h4.z, a[s]);
        a[s] = udot4_(wq[s][4*c+3], h4.w, a[s]);
      }
      uint4 w8 = *(const uint4*)(wl8 + 4 * c);
      a[8] = udot4_(w8.x, h4.x, a[8]);
      a[8] = udot4_(w8.y, h4.y, a[8]);
      a[8] = udot4_(w8.z, h4.z, a[8]);
      a[8] = udot4_(w8.w, h4.w, a[8]);
      if (tid < 192) {
        uint4 w9 = *(const uint4*)(wl9 + 4 * c);
        a[9] = udot4_(w9.x, h4.x, a[9]);
        a[9] = udot4_(w9.y, h4.y, a[9]);
        a[9] = udot4_(w9.z, h4.z, a[9]);
        a[9] = udot4_(w9.w, h4.w, a[9]);
      }
    }
    {
      unsigned hl = hb[24];
#pragma unroll
      for (int s = 0; s < 8; ++s) a[s] = udot4_(wq[s][24], hl, a[s]);
      a[8] = udot4_(wl8[24], hl, a[8]);
      if (tid < 192) a[9] = udot4_(wl9[24], hl, a[9]);
    }
    // butterfly across the quad: every lane gets full 400-k sums of all 10 slot-dots
#pragma unroll
    for (int s = 0; s < 10; ++s) {
      a[s] += __shfl_xor(a[s], 1);
      a[s] += __shfl_xor(a[s], 2);
    }
    // lane p writes slots s=p, s=p+4; lanes 0,1 also write s=8,9: d = grp + 128*s
    if (part == 0) {
      dots_i[grp]        = (int)a[0];
      dots_i[grp + 512]  = (int)a[4];
      dots_i[grp + 1024] = (int)a[8];
    } else if (part == 1) {
      dots_i[grp + 128]  = (int)a[1];
      dots_i[grp + 640]  = (int)a[5];
      if (grp < 48) dots_i[grp + 1152] = (int)a[9];
    } else if (part == 2) {
      dots_i[grp + 256]  = (int)a[2];
      dots_i[grp + 768]  = (int)a[6];
    } else {
      dots_i[grp + 384]  = (int)a[3];
      dots_i[grp + 896]  = (int)a[7];
    }
    __syncthreads();   // A: dots ready

    // ---------------- phase E: elementwise + repack ----------------
    if (tid < 300) acew[(t + 1) & 1][tid] = pf;
    unsigned ps = 0;
    if (tid < 400) {
      const int j = tid;
      const unsigned char* ab = (const unsigned char*)&acew[t & 1][0];
      float av = ((float)ab[j]       - P.a.z) * P.a.s;
      float cv = ((float)ab[400 + j] - P.c.z) * P.c.s;
      float ev = ((float)ab[800 + j] - P.e.z) * P.e.s;
      int hqs = HqS[t & 1];
      int Ib = dots_i[j]       - zwr * hqs + ic_l[j];
      int Id = dots_i[400 + j] - zwz * hqs + ic_l[400 + j];
      int If = dots_i[800 + j] - zwn * hqs + ic_l[800 + j];
      float bb = fq_((float)Ib * swr, P.b1.s, P.b1.z) + bias_l[j];
      bb = fq_(bb, P.b2.s, P.b2.z);
      float dd = fq_((float)Id * swz, P.d1.s, P.d1.z) + bias_l[400 + j];
      dd = fq_(dd, P.d2.s, P.d2.z);
      float ff = fq_((float)If * swn, P.f1.s, P.f1.z) + bias_l[800 + j];
      ff = fq_(ff, P.f2.s, P.f2.z);
      float r  = fq_(sigm_(fq_(av + bb, P.r1.s, P.r1.z)), P.r2.s, P.r2.z);
      float zz = fq_(sigm_(fq_(cv + dd, P.z1.s, P.z1.z)), P.z2.s, P.z2.z);
      float nn = fq_(tanhf(fq_(ev + fq_(r * ff, P.n1.s, P.n1.z), P.n2.s, P.n2.z)), P.n3.s, P.n3.z);
      float hold = ((float)hcode - P.rnn.z) * P.rnn.s;
      float hn2v = fq_(fq_(1.f - zz, P.hn1.s, P.hn1.z) * nn, P.hn2.s, P.hn2.z);
      float hn3v = fq_(zz * hold, P.hn3.s, P.hn3.z);
      float hnew = hn2v + hn3v;
      float qv = rintf(hnew / P.rnn.s) + P.rnn.z;
      qv = fminf(fmaxf(qv, 0.f), 255.f);
      unsigned code = (unsigned)qv;
      hcode = code;
      unsigned c1 = __shfl_down(code, 1);
      unsigned c2 = __shfl_down(code, 2);
      unsigned c3 = __shfl_down(code, 3);
      if ((j & 3) == 0) {
        unsigned packed = code | (c1 << 8) | (c2 << 16) | (c3 << 24);
        int wrd = j >> 2;                       // 0..99
        int pp = wrd / 25, off = wrd - pp * 25;
        hq[(t + 1) & 1][pp * 28 + off] = packed;
        *(unsigned*)(hs + ((size_t)t * 64 + b) * 400 + (wrd << 2)) = packed;
        ps = udot4_(packed, 0x01010101u, 0u);
      }
    }
#pragma unroll
    for (int off = 32; off; off >>= 1) ps += __shfl_down(ps, off);
    if ((tid & 63) == 0) atomicAdd(&HqS[(t + 1) & 1], (int)ps);
    __syncthreads();   // B: h(t+1), HqS(t+1), ace(t+1) ready
  }
}

// ---------------- host launch ----------------
extern "C" void kernel_launch(void* const* d_in, const int* in_sizes, int n_in,
                              void* d_out, int out_size, void* d_ws, size_t ws_size,
                              hipStream_t stream)
{
  const float* x    = (const float*)d_in[0];
  const float* Wfc1 = (const float*)d_in[1];
  const float* bfc1 = (const float*)d_in[2];
  const float* Wiz1 = (const float*)d_in[3];  const float* Whz1 = (const float*)d_in[4];
  const float* biz1 = (const float*)d_in[5];  const float* bhz1 = (const float*)d_in[6];
  const float* Wir1 = (const float*)d_in[7];  const float* Whr1 = (const float*)d_in[8];
  const float* bir1 = (const float*)d_in[9];  const float* bhr1 = (const float*)d_in[10];
  const float* Win1 = (const float*)d_in[11]; const float* Whn1 = (const float*)d_in[12];
  const float* bin1 = (const float*)d_in[13]; const float* bhn1 = (const float*)d_in[14];
  const float* Wiz2 = (const float*)d_in[15]; const float* Whz2 = (const float*)d_in[16];
  const float* biz2 = (const float*)d_in[17]; const float* bhz2 = (const float*)d_in[18];
  const float* Wir2 = (const float*)d_in[19]; const float* Whr2 = (const float*)d_in[20];
  const float* bir2 = (const float*)d_in[21]; const float* bhr2 = (const float*)d_in[22];
  const float* Win2 = (const float*)d_in[23]; const float* Whn2 = (const float*)d_in[24];
  const float* bin2 = (const float*)d_in[25]; const float* bhn2 = (const float*)d_in[26];
  const float* Wfc2 = (const float*)d_in[27]; const float* bfc2 = (const float*)d_in[28];
  const float* Wfc3 = (const float*)d_in[29]; const float* bfc3 = (const float*)d_in[30];
  const float* Wfc4 = (const float*)d_in[31]; const float* bfc4 = (const float*)d_in[32];
  float* out = (float*)d_out;

  char* wp = (char*)d_ws;
  auto alloc = [&](size_t bytes) -> void* {
    void* p = (void*)wp;
    wp += (bytes + 255) & ~(size_t)255;
    return p;
  };
  float* b1q = (float*)alloc(400 * 4);
  float* biq = (float*)alloc(2400 * 4);
  float* bhq = (float*)alloc(2400 * 4);
  float* b2q = (float*)alloc(600 * 4);
  float* b3q = (float*)alloc(600 * 4);
  float* b4q = (float*)alloc(257 * 4);
  unsigned char* WhC = (unsigned char*)alloc(960000);
  int* colsum = (int*)alloc(2400 * 4);
  signed char* WiT = (signed char*)alloc(7 * 400 * 464);  // 6 proj + W1
  signed char* Bt2 = (signed char*)alloc(600 * 464);      // W2 (i8)
  bf16_t* Bt3 = (bf16_t*)alloc(600 * 608 * 2);            // W3 bf16 codes
  bf16_t* Bt4 = (bf16_t*)alloc(257 * 608 * 2);            // W4 bf16 codes
  int* cwi = (int*)alloc((7 * 400 + 600) * 4);
  int* rsX1 = (int*)alloc(64000 * 4);
  int* rsX  = (int*)alloc(64000 * 4);
  int* rsH  = (int*)alloc(64000 * 4);
  int* rsH2 = (int*)alloc(64000 * 4);
  unsigned char* xsq = (unsigned char*)alloc(25600000);
  unsigned char* Aq  = (unsigned char*)alloc(25600000);
  unsigned char* Cq  = (unsigned char*)alloc(25600000);
  unsigned char* Eq  = (unsigned char*)alloc(25600000);
  unsigned char* hs1 = (unsigned char*)alloc(25600000);
  unsigned char* hs2 = (unsigned char*)alloc(25600000);
  // overlays on dead regions
  float* y2c = (float*)Aq;                       // 38.4 MB (A/C/E dead during FC chain)
  float* y3c = (float*)(Aq + 38400000);          // 38.4 MB
  unsigned char* xcq = hs1;                      // x codes [64000][464] (hs1 dead pre-rec1)

  // ---- merged prep: all 16 bias fq in one launch ----
  BJobs bj;
  bj.j[0]  = { bfc1, b1q,        400, Zbfc1.s, Zbfc1.z };
  bj.j[1]  = { bir1, biq + 0,    400, Zbir1.s, Zbir1.z };
  bj.j[2]  = { biz1, biq + 400,  400, Zbiz1.s, Zbiz1.z };
  bj.j[3]  = { bin1, biq + 800,  400, Zbin1.s, Zbin1.z };
  bj.j[4]  = { bir2, biq + 1200, 400, Zbir2.s, Zbir2.z };
  bj.j[5]  = { biz2, biq + 1600, 400, Zbiz2.s, Zbiz2.z };
  bj.j[6]  = { bin2, biq + 2000, 400, Zbin2.s, Zbin2.z };
  bj.j[7]  = { bhr1, bhq + 0,    400, Zbhr1.s, Zbhr1.z };
  bj.j[8]  = { bhz1, bhq + 400,  400, Zbhz1.s, Zbhz1.z };
  bj.j[9]  = { bhn1, bhq + 800,  400, Zbhn1.s, Zbhn1.z };
  bj.j[10] = { bhr2, bhq + 1200, 400, Zbhr2.s, Zbhr2.z };
  bj.j[11] = { bhz2, bhq + 1600, 400, Zbhz2.s, Zbhz2.z };
  bj.j[12] = { bhn2, bhq + 2000, 400, Zbhn2.s, Zbhn2.z };
  bj.j[13] = { bfc2, b2q,        600, Zbfc2.s, Zbfc2.z };
  bj.j[14] = { bfc3, b3q,        600, Zbfc3.s, Zbfc3.z };
  bj.j[15] = { bfc4, b4q,        257, Zbfc4.s, Zbfc4.z };
  kbias<<<dim3(16), dim3(256), 0, stream>>>(bj);

  W6 wh = { { Whr1, Whz1, Whn1, Whr2, Whz2, Whn2 },
            { ZWhr1.s, ZWhz1.s, ZWhn1.s, ZWhr2.s, ZWhz2.s, ZWhn2.s },
            { ZWhr1.z, ZWhz1.z, ZWhn1.z, ZWhr2.z, ZWhz2.z, ZWhn2.z } };
  kwhc6<<<dim3(3750), dim3(256), 0, stream>>>(wh, WhC);
  kcolsum<<<dim3(10), dim3(256), 0, stream>>>(WhC, colsum);

  hipMemsetAsync(cwi, 0, (7 * 400 + 600) * 4, stream);
  W6 wi = { { Wir1, Wiz1, Win1, Wir2, Wiz2, Win2 },
            { ZWir1.s, ZWiz1.s, ZWin1.s, ZWir2.s, ZWiz2.s, ZWin2.s },
            { ZWir1.z, ZWiz1.z, ZWin1.z, ZWir2.z, ZWiz2.z, ZWin2.z } };
  kwic6<<<dim3(625), dim3(256), 0, stream>>>(wi, WiT, cwi);
  kwic<<<dim3(625), dim3(256), 0, stream>>>(Wfc1, WiT + (size_t)6 * 185600, cwi + 2400, ZW1.s, ZW1.z, 257, 400);
  kwic<<<dim3(625), dim3(256), 0, stream>>>(Wfc2, Bt2, cwi + 2800, ZWfc2.s, ZWfc2.z, 400, 600);
  kwbf<<<dim3(625), dim3(256), 0, stream>>>(Wfc3, Bt3, ZWfc3.s, ZWfc3.z, 600, 600);
  kwbf<<<dim3(625), dim3(256), 0, stream>>>(Wfc4, Bt4, ZWfc4.s, ZWfc4.z, 600, 257);

  auto gi8 = [&](const unsigned char* A, int strideA, int aw4, const int* rs,
                 const signed char* Bt, const int* cs, const float* bias,
                 unsigned char* oU8, float* oF, int M, int N, int outStride, int epMode,
                 SZ a, SZ w, int Kreal, float ss, SZ e1, SZ e2) {
    int czw = 128 - (int)w.z, cza = 128 - (int)a.z;
    int cconst = Kreal * cza * czw;
    int nb = (N + 79) / 80;
    gemm_i8<<<dim3((M / 64) * nb), dim3(256), 0, stream>>>(
        A, strideA, aw4, rs, Bt, cs, bias, oU8, oF, N, nb, outStride, epMode,
        czw, cza, cconst, ss, e1.s, e1.z, e2.s, e2.z);
  };

  // ---- FC1 (exact-int i8): x codes -> xsq codes ----
  kxq<<<dim3((64000 * 464 + 255) / 256), dim3(256), 0, stream>>>(x, xcq, Zx.s, Zx.z);
  krsum<<<dim3(250), dim3(256), 0, stream>>>(xcq, rsX1, 29);
  gi8(xcq, 464, 29, rsX1, WiT + (size_t)6 * 185600, cwi + 2400, b1q,
      xsq, nullptr, 64000, 400, 400, 0, Zx, ZW1, 257, Zx.s * ZW1.s, Zfc1mm, Zfc1add);

  // ---- GRU layer 1 input projections (i8) ----
  krsum<<<dim3(250), dim3(256), 0, stream>>>(xsq, rsX, 25);
  gi8(xsq, 400, 25, rsX, WiT + (size_t)0 * 185600, cwi + 0,    biq + 0,   Aq, nullptr,
      64000, 400, 400, 0, Zfc1add, ZWir1, 400, Zfc1add.s * ZWir1.s, Za_1, Za1);
  gi8(xsq, 400, 25, rsX, WiT + (size_t)1 * 185600, cwi + 400,  biq + 400, Cq, nullptr,
      64000, 400, 400, 0, Zfc1add, ZWiz1, 400, Zfc1add.s * ZWiz1.s, Zc_1, Zc1);
  gi8(xsq, 400, 25, rsX, WiT + (size_t)2 * 185600, cwi + 800,  biq + 800, Eq, nullptr,
      64000, 400, 400, 0, Zfc1add, ZWin1, 400, Zfc1add.s * ZWin1.s, Ze_1, Ze1);
  // ---- GRU layer 1 recurrence (single-block-per-batch) ----
  gru_rec512<<<dim3(64), dim3(512), 0, stream>>>(WhC, colsum, Aq, Cq, Eq,
                                                 bhq + 0, bhq + 400, bhq + 800,
                                                 hs1, PL1);
  // ---- GRU layer 2 input projections (i8) ----
  krsum<<<dim3(250), dim3(256), 0, stream>>>(hs1, rsH, 25);
  gi8(hs1, 400, 25, rsH, WiT + (size_t)3 * 185600, cwi + 1200, biq + 1200, Aq, nullptr,
      64000, 400, 400, 0, Zrnn, ZWir2, 400, Zrnn.s * ZWir2.s, Za_2, Za2);
  gi8(hs1, 400, 25, rsH, WiT + (size_t)4 * 185600, cwi + 1600, biq + 1600, Cq, nullptr,
      64000, 400, 400, 0, Zrnn, ZWiz2, 400, Zrnn.s * ZWiz2.s, Zc_2, Zc2);
  gi8(hs1, 400, 25, rsH, WiT + (size_t)5 * 185600, cwi + 2000, biq + 2000, Eq, nullptr,
      64000, 400, 400, 0, Zrnn, ZWin2, 400, Zrnn.s * ZWin2.s, Ze_2, Ze1);
  // ---- GRU layer 2 recurrence ----
  gru_rec512<<<dim3(64), dim3(512), 0, stream>>>(WhC + 480000, colsum + 1200, Aq, Cq, Eq,
                                                 bhq + 1200, bhq + 1600, bhq + 2000,
                                                 hs2, PL2);
  // ---- FC2 (i8) -> FC3 -> FC4 (bf16x2 MFMA) in 4 row chunks ----
  krsum<<<dim3(250), dim3(256), 0, stream>>>(hs2, rsH2, 25);
  for (int rc = 0; rc < 4; ++rc) {
    const unsigned char* a2 = hs2 + (size_t)rc * 16000 * 400;
    gi8(a2, 400, 25, rsH2 + rc * 16000, Bt2, cwi + 2800, b2q, nullptr, y2c,
        16000, 600, 600, 2, Zrnn, ZWfc2, 400, Zrnn.s * ZWfc2.s, Zrnn, Zrnn);
    gemm_bf<<<dim3(125 * 5), dim3(512), 0, stream>>>(y2c, Bt3, b3q, y3c, 600, 5, 2, 0, ZWfc3.s);
    gemm_bf<<<dim3(125 * 3), dim3(512), 0, stream>>>(y3c, Bt4, b4q, out, 257, 3, 3, rc * 16000, ZWfc4.s);
  }
  (void)in_sizes; (void)n_in; (void)out_size; (void)ws_size;
}

// Round 4
// 6849.921 us; speedup vs baseline: 1.7853x; 1.7853x over previous
//
#include <hip/hip_runtime.h>
#include <math.h>

#define DEV static __device__ __forceinline__

typedef int v4i __attribute__((ext_vector_type(4)));
typedef float v4f __attribute__((ext_vector_type(4)));
typedef __bf16 bf16_t;
typedef __bf16 v8bf __attribute__((ext_vector_type(8)));

// ---------------- calibration (s, z) constants, computed like the reference ----------------
struct SZ { float s, z; };

constexpr double cfloor_(double v){ long long i=(long long)v; return ((double)i > v) ? (double)(i-1) : (double)i; }
constexpr double cround_(double v){            // round half-to-even (Python round / nearbyint)
  double fl = cfloor_(v); double fr = v - fl;
  return (fr > 0.5) ? fl + 1.0 : (fr < 0.5 ? fl : ((((long long)fl) & 1LL) == 0 ? fl : fl + 1.0));
}
constexpr SZ mksz(double mn, double mx){
  double s = (mx - mn) / 255.0;
  double z = cround_(-mn / s);
  return SZ{ (float)s, (float)z };
}

constexpr SZ Zx     = mksz(-0.0025095, 0.0022181);
constexpr SZ ZW1    = mksz(-0.22075387835502625, 0.208940327167511);
constexpr SZ Zfc1mm = mksz(-0.00291599917, 0.0017367251);
constexpr SZ Zbfc1  = mksz(-0.48688140511512756, 0.5176185369491577);
constexpr SZ Zfc1add= mksz(-0.48778465390205383, 0.5181604027748108);
// layer-1 weights/biases
constexpr SZ ZWiz1 = mksz(-0.43284985423088074, 0.46175122261047363);
constexpr SZ ZWir1 = mksz(-0.34401071071624756, 0.29191476106643677);
constexpr SZ ZWin1 = mksz(-0.3236880302429199, 0.39607325196266174);
constexpr SZ ZWhz1 = mksz(-1.8417714834213257, 1.7173254489898682);
constexpr SZ ZWhr1 = mksz(-1.1574513912200928, 1.0300449132919312);
constexpr SZ ZWhn1 = mksz(-0.7756922245025635, 0.9530389308929443);
constexpr SZ Zbiz1 = mksz(-0.5063393712043762, 0.36664387583732605);
constexpr SZ Zbir1 = mksz(-0.07920225709676743, 0.20611026883125305);
constexpr SZ Zbin1 = mksz(-0.5539973378181458, 0.17938342690467834);
constexpr SZ Zbhz1 = mksz(-0.5337516665458679, 0.4148772358894348);
constexpr SZ Zbhr1 = mksz(-0.07688436657190323, 0.14814253151416779);
constexpr SZ Zbhn1 = mksz(-0.7828555107116699, 0.9008108973503113);
// layer-2 weights/biases
constexpr SZ ZWiz2 = mksz(-0.9102030992507935, 0.9408696889877319);
constexpr SZ ZWir2 = mksz(-0.9560997486114502, 0.6683358550071716);
constexpr SZ ZWin2 = mksz(-0.4721935987472534, 0.48561596870422363);
constexpr SZ ZWhz2 = mksz(-1.2992678880691528, 1.2991048097610474);
constexpr SZ ZWhr2 = mksz(-0.8318714499473572, 1.1085889339447021);
constexpr SZ ZWhn2 = mksz(-0.955470085144043, 1.046797513961792);
constexpr SZ Zbiz2 = mksz(-0.44805487990379333, 0.1560053527355194);
constexpr SZ Zbir2 = mksz(-0.08767592161893845, 0.11347303539514542);
constexpr SZ Zbin2 = mksz(-0.239909827709198, 0.12033259868621826);
constexpr SZ Zbhz2 = mksz(-0.43745461106300354, 0.12699371576309204);
constexpr SZ Zbhr2 = mksz(-0.09617264568805695, 0.07690174877643585);
constexpr SZ Zbhn2 = mksz(-0.17204178869724274, 0.19739042222499847);
// fc tail
constexpr SZ ZWfc2 = mksz(-1.3657219409942627, 1.158295750617981);
constexpr SZ Zbfc2 = mksz(-0.1750922054052353, 0.1385071724653244);
constexpr SZ ZWfc3 = mksz(-3.1666038036346436, 2.5026357173919678);
constexpr SZ Zbfc3 = mksz(-0.10188056528568268, 0.0899151861667633);
constexpr SZ ZWfc4 = mksz(-1.300571084022522, 1.928941249847412);
constexpr SZ Zbfc4 = mksz(-0.10699586570262909, 0.04597663879394531);
// gru1 stages
constexpr SZ Za_1 = mksz(-0.6389939785003662, 0.7715625762939453);
constexpr SZ Za1  = mksz(-0.6046768426895142, 0.8871182203292847);
constexpr SZ Zb_1 = mksz(-0.004922409541904926, 0.004103424027562141);
constexpr SZ Zb1  = mksz(-0.07475128024816513, 0.14630259573459625);
constexpr SZ Zc_1 = mksz(-1.5660111904144287, 1.0454494953155518);
constexpr SZ Zc1  = mksz(-1.9779117107391357, 1.3700535297393799);
constexpr SZ Zd_1 = mksz(-0.008429044857621193, 0.006403823848813772);
constexpr SZ Zd1  = mksz(-0.5529640316963196, 0.41507571935653687);
constexpr SZ Ze_1 = mksz(-1.3637111186981201, 1.018247127532959);
constexpr SZ Ze1  = mksz(-1.8583884239196777, 1.1587692499160767);
constexpr SZ Zf_1 = mksz(-0.005411399528384209, 0.0061536869034171104);
constexpr SZ Zf1  = mksz(-0.7833794355392456, 0.8978855013847351);
constexpr SZ Zr_1 = mksz(-0.6226556301116943, 0.9800534844398499);
constexpr SZ Zr1  = mksz(0.3491777181625366, 0.7271188497543335);
constexpr SZ Zz_1 = mksz(-2.392332077026367, 1.7851293087005615);
constexpr SZ Zz1  = mksz(0.08375928550958633, 0.856329083442688);
constexpr SZ Zn11 = mksz(-0.5516456365585327, 0.4556601643562317);
constexpr SZ Zn21 = mksz(-2.4100341796875, 1.1423156261444092);
constexpr SZ Zn1  = mksz(-0.983996570110321, 0.8151924014091492);
constexpr SZ Zhn11= mksz(0.143670916557312, 0.9162406921386719);
constexpr SZ Zhn21= mksz(-0.9015777111053467, 0.45391541719436646);
constexpr SZ Zhn31= mksz(-0.0016954239690676332, 0.0016671211924403906);
constexpr SZ Zrnn = mksz(-0.9016271829605103, 0.4546271562576294);
// gru2 explicit entries (the rest fall back to gru1 values, incl. rnn2GRU)
constexpr SZ Za_2 = mksz(-0.681461751461029, 0.9113116264343262);
constexpr SZ Za2  = mksz(-0.7149235010147095, 0.908741295337677);
constexpr SZ Zb_2 = mksz(-0.005148397758603096, 0.011014967225492);
constexpr SZ Zb2g = mksz(-0.09436552226543427, 0.07623167335987091);
constexpr SZ Zc_2 = mksz(-1.2279887199401855, 1.1102137565612793);
constexpr SZ Zc2  = mksz(-1.6760436296463013, 1.200895071029663);
constexpr SZ Zd_2 = mksz(-0.008141756057739258, 0.00894666276872158);
constexpr SZ Zd2  = mksz(-0.43875735998153687, 0.1262134611606598);
constexpr SZ Ze_2 = mksz(-0.6732944250106812, 0.6314664483070374);

struct RecP {
  SZ wr, wz, wn;
  SZ a, c, e;
  SZ b1, b2, d1, d2, f1, f2;
  SZ r1, r2, z1, z2;
  SZ n1, n2, n3;
  SZ hn1, hn2, hn3, rnn;
};
constexpr RecP PL1 = { ZWhr1, ZWhz1, ZWhn1, Za1, Zc1, Ze1, Zb_1, Zb1, Zd_1, Zd1, Zf_1, Zf1,
                       Zr_1, Zr1, Zz_1, Zz1, Zn11, Zn21, Zn1, Zhn11, Zhn21, Zhn31, Zrnn };
constexpr RecP PL2 = { ZWhr2, ZWhz2, ZWhn2, Za2, Zc2, Ze1, Zb_2, Zb2g, Zd_2, Zd2, Zf_1, Zf1,
                       Zr_1, Zr1, Zz_1, Zz1, Zn11, Zn21, Zn1, Zhn11, Zhn21, Zhn31, Zrnn };

// ---------------- device helpers ----------------
DEV float fq_(float x, float s, float z){
  float q = rintf(x / s) + z;
  q = fminf(fmaxf(q, 0.f), 255.f);
  return (q - z) * s;
}
DEV float sigm_(float v){ return 1.f / (1.f + expf(-v)); }

DEV unsigned udot4_(unsigned a, unsigned b, unsigned c){
#if defined(__has_builtin) && __has_builtin(__builtin_amdgcn_udot4)
  return __builtin_amdgcn_udot4(a, b, c, false);
#else
  return c + (a & 255u) * (b & 255u) + ((a >> 8) & 255u) * ((b >> 8) & 255u)
           + ((a >> 16) & 255u) * ((b >> 16) & 255u) + (a >> 24) * (b >> 24);
#endif
}

// ---------------- prep kernels ----------------
struct BJob { const float* src; float* dst; int n; float s; float z; };
struct BJobs { BJob j[16]; };
__global__ __launch_bounds__(256) void kbias(BJobs jobs){
  BJob J = jobs.j[blockIdx.x];
  for (int i = threadIdx.x; i < J.n; i += 256) J.dst[i] = fq_(J.src[i], J.s, J.z);
}

struct W6 { const float* W[6]; float s[6]; float z[6]; };
// six Wh [400][400] (k-major) -> u8 codes, column-major [m][j][k]
__global__ __launch_bounds__(256) void kwhc6(W6 jb, unsigned char* __restrict__ dst){
  int i = blockIdx.x * 256 + threadIdx.x;
  if (i < 960000) {
    int m = i / 160000, r = i - m * 160000;
    int j = r / 400, k = r - j * 400;
    float q = rintf(jb.W[m][k * 400 + j] / jb.s[m]) + jb.z[m];
    q = fminf(fmaxf(q, 0.f), 255.f);
    dst[i] = (unsigned char)q;
  }
}
__global__ __launch_bounds__(256) void kcolsum(const unsigned char* __restrict__ WhC, int* __restrict__ cs){
  int i = blockIdx.x * 256 + threadIdx.x;
  if (i < 2400) {
    const unsigned char* p = WhC + (size_t)i * 400;
    int s = 0;
    for (int k = 0; k < 400; ++k) s += p[k];
    cs[i] = s;
  }
}
// six Wi [400][400] -> transposed biased codes [m][n][464] + colsum(q-128)
__global__ __launch_bounds__(256) void kwic6(W6 jb, signed char* __restrict__ WiT, int* __restrict__ cs){
  for (int idx = blockIdx.x * 256 + threadIdx.x; idx < 960000; idx += gridDim.x * 256) {
    int m = idx / 160000, r = idx - m * 160000;
    int k = r / 400, n = r - k * 400;
    float q = rintf(jb.W[m][r] / jb.s[m]) + jb.z[m];
    q = fminf(fmaxf(q, 0.f), 255.f);
    int qi = (int)q;
    WiT[(size_t)m * 185600 + (size_t)n * 464 + k] = (signed char)(qi ^ 0x80);
    atomicAdd(&cs[m * 400 + n], qi - 128);
  }
  for (int idx = blockIdx.x * 256 + threadIdx.x; idx < 153600; idx += gridDim.x * 256) {
    int m = idx / 25600, r = idx - m * 25600;
    int n = r / 64, p = r - n * 64;
    WiT[(size_t)m * 185600 + (size_t)n * 464 + 400 + p] = 0;
  }
}
// W [K][N] f32 -> transposed biased codes Bt [N][464] + colsum(q-128)  (FC1/FC2)
__global__ __launch_bounds__(256) void kwic(const float* __restrict__ W, signed char* __restrict__ Bt,
                                            int* __restrict__ cs, float s, float z, int K, int N){
  int total1 = K * N, total2 = (464 - K) * N;
  for (int idx = blockIdx.x * 256 + threadIdx.x; idx < total1; idx += gridDim.x * 256) {
    int k = idx / N, n = idx - k * N;
    float q = rintf(W[idx] / s) + z;
    q = fminf(fmaxf(q, 0.f), 255.f);
    int qi = (int)q;
    Bt[(size_t)n * 464 + k] = (signed char)(qi ^ 0x80);
    atomicAdd(&cs[n], qi - 128);
  }
  for (int idx = blockIdx.x * 256 + threadIdx.x; idx < total2; idx += gridDim.x * 256) {
    int n = idx / (464 - K), k = K + (idx - n * (464 - K));
    Bt[(size_t)n * 464 + k] = 0;
  }
}
// W [K][N] f32 -> transposed bf16 INTEGER codes (q-z) in [N][608] (pad 0)  (FC3/FC4)
__global__ __launch_bounds__(256) void kwbf(const float* __restrict__ W, bf16_t* __restrict__ Bt,
                                            float s, float z, int K, int N){
  int total1 = K * N, total2 = (608 - K) * N;
  for (int idx = blockIdx.x * 256 + threadIdx.x; idx < total1; idx += gridDim.x * 256) {
    int k = idx / N, n = idx - k * N;
    float q = rintf(W[idx] / s) + z;
    q = fminf(fmaxf(q, 0.f), 255.f);
    Bt[(size_t)n * 608 + k] = (bf16_t)(q - z);     // integer in [-255,255]: exact in bf16
  }
  for (int idx = blockIdx.x * 256 + threadIdx.x; idx < total2; idx += gridDim.x * 256) {
    int n = idx / (608 - K), k = K + (idx - n * (608 - K));
    Bt[(size_t)n * 608 + k] = (bf16_t)0.f;
  }
}
// quantize x [B,T,F] -> xcq codes [T*64+b][464] (pads = code 128)
__global__ __launch_bounds__(256) void kxq(const float* __restrict__ x, unsigned char* __restrict__ xcq,
                                           float s, float z){
  int idx = blockIdx.x * 256 + threadIdx.x;
  if (idx < 64000 * 464) {
    int row = idx / 464, c = idx - row * 464;
    unsigned char code = 128;
    if (c < 257) {
      int bb = row & 63, tt = row >> 6;
      float q = rintf(x[((size_t)bb * 1000 + tt) * 257 + c] / s) + z;
      q = fminf(fmaxf(q, 0.f), 255.f);
      code = (unsigned char)q;
    }
    xcq[idx] = code;
  }
}
// per-row sums of (q-128) over w4 uint4-words of u8 codes (pads must be code 128)
__global__ __launch_bounds__(256) void krsum(const unsigned char* __restrict__ A, int* __restrict__ rs,
                                             int w4){
  int r = blockIdx.x * 256 + threadIdx.x;
  const unsigned* p = (const unsigned*)(A + (size_t)r * (w4 * 16));
  unsigned s = 0;
  for (int i = 0; i < w4 * 4; ++i) s = udot4_(p[i], 0x01010101u, s);
  rs[r] = (int)s - 128 * 4 * (w4 * 4);
}
// init all 4 ring slots of both directions/layers with tag-0 code0 payloads
__global__ __launch_bounds__(256) void kinit2(unsigned long long* __restrict__ hp1,
                                              unsigned long long* __restrict__ hp2, unsigned code){
  int i = blockIdx.x * 256 + threadIdx.x;
  if (i < 25600) {
    unsigned long long w = (unsigned long long)(code * 0x01010101u);
    hp1[i] = w; hp2[i] = w;
  }
}

// ---------------- exact-int i8 MFMA GEMM ----------------
// BM=64, BN=80, K padded to 448. dot_int = S + czw*RA' + cza*CW' + cconst.
__global__ __launch_bounds__(256) void gemm_i8(
    const unsigned char* __restrict__ Au8, int strideA, int aw4,
    const int* __restrict__ rowsum,
    const signed char* __restrict__ Bt, const int* __restrict__ colsum,
    const float* __restrict__ bias,
    unsigned char* __restrict__ outU8, float* __restrict__ outF,
    int N, int nb, int outStride, int epMode,
    int czw, int cza, int cconst, float ss,
    float e1S, float e1Z, float e2S, float e2Z)
{
  __shared__ __align__(16) signed char Asl[64 * 464];
  __shared__ __align__(16) signed char Bsl[80 * 464];
  const int tid = threadIdx.x;
  const int bm = blockIdx.x / nb;
  const int bn = blockIdx.x - bm * nb;
  const int m0 = bm * 64;
  const int n0 = bn * 80;
  for (int i = tid; i < 80 * 29; i += 256) {
    int r = i / 29, c = i - r * 29;
    uint4 v;
    if (n0 + r < N) v = *(const uint4*)(Bt + (size_t)(n0 + r) * 464 + c * 16);
    else { v.x = 0u; v.y = 0u; v.z = 0u; v.w = 0u; }
    *(uint4*)(Bsl + (size_t)r * 464 + c * 16) = v;
  }
  for (int i = tid; i < 64 * 29; i += 256) {
    int r = i / 29, c = i - r * 29;
    uint4 v;
    if (c < aw4) {
      v = *(const uint4*)(Au8 + (size_t)(m0 + r) * strideA + c * 16);
      v.x ^= 0x80808080u; v.y ^= 0x80808080u; v.z ^= 0x80808080u; v.w ^= 0x80808080u;
    } else { v.x = 0u; v.y = 0u; v.z = 0u; v.w = 0u; }
    *(uint4*)(Asl + (size_t)r * 464 + c * 16) = v;
  }
  __syncthreads();
  const int wv = tid >> 6, ln = tid & 63;
  const int lr = ln & 15;
  const int lk = ln >> 4;
  v4i acc[5];
#pragma unroll
  for (int j = 0; j < 5; ++j) { acc[j][0] = 0; acc[j][1] = 0; acc[j][2] = 0; acc[j][3] = 0; }
#pragma unroll
  for (int kc = 0; kc < 7; ++kc) {
    int kb = kc * 64 + lk * 16;
    v4i a = *(const v4i*)(Asl + (size_t)(wv * 16 + lr) * 464 + kb);
#pragma unroll
    for (int j = 0; j < 5; ++j) {
      v4i b = *(const v4i*)(Bsl + (size_t)(j * 16 + lr) * 464 + kb);
      acc[j] = __builtin_amdgcn_mfma_i32_16x16x64_i8(a, b, acc[j], 0, 0, 0);
    }
  }
#pragma unroll
  for (int reg = 0; reg < 4; ++reg) {
    int row = m0 + wv * 16 + lk * 4 + reg;
    int RA = rowsum[row];
#pragma unroll
    for (int j = 0; j < 5; ++j) {
      int col = n0 + j * 16 + lr;
      if (col >= N) continue;
      int I = acc[j][reg] + czw * RA + cza * colsum[col] + cconst;
      float v = (float)I * ss;
      if (epMode == 0) {
        v = fq_(v, e1S, e1Z) + bias[col];
        float q = rintf(v / e2S) + e2Z;
        q = fminf(fmaxf(q, 0.f), 255.f);
        outU8[(size_t)row * outStride + col] = (unsigned char)q;
      } else {
        v += bias[col];
        v = fmaxf(v, 0.f);
        outF[(size_t)row * outStride + col] = v;
      }
    }
  }
}

// ---------------- bf16x2-split MFMA GEMM (FC3/FC4) ----------------
__global__ __launch_bounds__(512) void gemm_bf(
    const float* __restrict__ A, const bf16_t* __restrict__ Bt,
    const float* __restrict__ bias, float* __restrict__ outF,
    int N, int nb, int epMode, int rowOff, float sc)
{
  __shared__ __align__(16) bf16_t Bs[128 * 616];   // row stride 616 (conflict-free b128)
  const int tid = threadIdx.x;
  const int bm = blockIdx.x / nb;
  const int bn = blockIdx.x - bm * nb;
  const int m0 = bm * 128;
  const int n0 = bn * 128;
  for (int i = tid; i < 128 * 76; i += 512) {
    int r = i / 76, c = i - r * 76;
    uint4 v; v.x = 0u; v.y = 0u; v.z = 0u; v.w = 0u;
    if (n0 + r < N) v = *(const uint4*)((const char*)(Bt + (size_t)(n0 + r) * 608) + c * 16);
    *(uint4*)((char*)(Bs + (size_t)r * 616) + c * 16) = v;
  }
  __syncthreads();
  const int wv = tid >> 6, ln = tid & 63;
  const int lr = ln & 15, quad = ln >> 4;
  const float* arp = A + (size_t)(m0 + wv * 16 + lr) * 600;
  v4f acc[8];
#pragma unroll
  for (int j = 0; j < 8; ++j) { acc[j][0] = 0.f; acc[j][1] = 0.f; acc[j][2] = 0.f; acc[j][3] = 0.f; }
  for (int kc = 0; kc < 19; ++kc) {
    int kb = kc * 32 + quad * 8;
    float af[8];
    if (kc == 18 && quad == 3) {
#pragma unroll
      for (int j = 0; j < 8; ++j) af[j] = 0.f;
    } else {
      *(float4*)&af[0] = *(const float4*)(arp + kb);
      *(float4*)&af[4] = *(const float4*)(arp + kb + 4);
    }
    v8bf ah, al;
#pragma unroll
    for (int j = 0; j < 8; ++j) {
      float xx = af[j];
      bf16_t h = (bf16_t)xx;
      ah[j] = h;
      al[j] = (bf16_t)(xx - (float)h);
    }
#pragma unroll
    for (int nf = 0; nf < 8; ++nf) {
      v8bf bfrag = *(const v8bf*)(Bs + (size_t)(nf * 16 + lr) * 616 + kc * 32 + quad * 8);
      acc[nf] = __builtin_amdgcn_mfma_f32_16x16x32_bf16(ah, bfrag, acc[nf], 0, 0, 0);
      acc[nf] = __builtin_amdgcn_mfma_f32_16x16x32_bf16(al, bfrag, acc[nf], 0, 0, 0);
    }
  }
#pragma unroll
  for (int nf = 0; nf < 8; ++nf) {
    int col = n0 + nf * 16 + lr;
    if (col >= N) continue;
    float bcol = bias[col];
#pragma unroll
    for (int reg = 0; reg < 4; ++reg) {
      int row = m0 + wv * 16 + quad * 4 + reg;
      float v = acc[nf][reg] * sc + bcol;
      if (epMode == 2) {
        v = fmaxf(v, 0.f);
        outF[(size_t)row * N + col] = v;
      } else {
        v = sigm_(v);
        int rg = rowOff + row;
        int tt = rg >> 6, bb = rg & 63;
        outF[((size_t)bb * 1000 + tt) * 257 + col] = v;
      }
    }
  }
}

// ---------------- GRU recurrence: 2 blocks per batch, weights in VGPRs+LDS ----------------
// 128 blocks x 512 threads. Block (sl, b): sl = blockIdx>>6, b = blockIdx&63 -- the pair
// (b, 64+b) shares blockIdx%8, i.e. (likely) one XCD. Each block owns j in
// [sl*200, sl*200+200) for ALL 3 gates: 600 dots x 4 k-quarters = 2400 slots.
// Slots q = tid + 512*s for s=0..3 in REGISTERS (wq[4][25] = 100 VGPRs, fits the
// 128-VGPR budget the RA actually gives), slot q = 2048+tid (tid<352) in LDS.
// part (q&3) == (tid&3): fixed 25-word h k-slice per thread; quad butterfly completes
// dots. Per step the pair exchanges 50 h-code words via a tagged-u64 depth-4 ring
// (R0's proven pattern); wave 7 polls, copies into hq, computes HqS, releases an LDS
// flag. Skew between partners is bounded to 1 step => no ring overwrite.
__global__ __launch_bounds__(512)
__attribute__((amdgpu_num_vgpr(160)))
void gru_rec2b(
    const unsigned char* __restrict__ WhC, const int* __restrict__ colsum,
    const unsigned char* __restrict__ Aq, const unsigned char* __restrict__ Cq,
    const unsigned char* __restrict__ Eq,
    const float* __restrict__ bhr, const float* __restrict__ bhz, const float* __restrict__ bhn,
    unsigned char* __restrict__ hs, unsigned long long* __restrict__ hpub, RecP P)
{
  __shared__ __align__(16) unsigned Wl[352 * 28];   // 39,424 B LDS quarter-slots
  __shared__ __align__(16) unsigned hq[2][4 * 28];  // h codes, [part][25 words] stride 28
  __shared__ int dots_i[600];
  __shared__ unsigned acew[2][150];                 // own-j a/c/e codes (3 gates x 50 words)
  __shared__ int ic_l[600];
  __shared__ float bias_l[600];
  __shared__ int HqS_s;
  __shared__ int flag;

  const int tid = threadIdx.x;
  const int sl = blockIdx.x >> 6;
  const int b  = blockIdx.x & 63;
  const unsigned* Wu = (const unsigned*)WhC;

  // ---- register-resident weight quarters (4 x 25 dwords = 100 VGPRs) ----
  unsigned wq[4][25];
#pragma unroll
  for (int s = 0; s < 4; ++s) {
    int q = tid + 512 * s;
    int ld = q >> 2, p = q & 3;
    int g = (ld >= 400) ? 2 : (ld >= 200 ? 1 : 0);
    int col = g * 400 + sl * 200 + (ld - g * 200);
    const unsigned* src = Wu + col * 100 + p * 25;
#pragma unroll
    for (int w = 0; w < 25; ++w) wq[s][w] = src[w];
  }
  // ---- LDS weight quarters: q = 2048 + tid (tid < 352) ----
  if (tid < 352) {
    int q = 2048 + tid;
    int ld = q >> 2, p = q & 3;
    int g = (ld >= 400) ? 2 : (ld >= 200 ? 1 : 0);
    int col = g * 400 + sl * 200 + (ld - g * 200);
    const unsigned* src = Wu + col * 100 + p * 25;
    for (int w = 0; w < 25; ++w) Wl[tid * 28 + w] = src[w];
  }
  // ---- per-dot correction + bias tables (local dot ld = g*200 + jl) ----
  const int zh = (int)P.rnn.z;
  for (int ld = tid; ld < 600; ld += 512) {
    int g = (ld >= 400) ? 2 : (ld >= 200 ? 1 : 0);
    int jl = ld - g * 200;
    int col = g * 400 + sl * 200 + jl;
    int zw = (g == 0) ? (int)P.wr.z : (g == 1) ? (int)P.wz.z : (int)P.wn.z;
    ic_l[ld] = -zh * colsum[col] + 400 * zh * zw;
    bias_l[ld] = ((g == 0) ? bhr : (g == 1) ? bhz : bhn)[sl * 200 + jl];
  }
  // ---- h0 / ace(t=0) / flag init ----
  const unsigned code0 = (unsigned)fminf(fmaxf(P.rnn.z, 0.f), 255.f);
  for (int i = tid; i < 100; i += 512)
    hq[0][(i / 25) * 28 + (i % 25)] = code0 * 0x01010101u;
  if (tid == 0) flag = -1;
  const unsigned char* psrc = nullptr;
  int poff = 0;
  if (tid < 150) {
    int g = tid / 50, w = tid - g * 50;
    psrc = (g == 0) ? Aq : (g == 1) ? Cq : Eq;
    poff = (sl * 50 + w) * 4;
    acew[0][tid] = *(const unsigned*)(psrc + (size_t)b * 400 + poff);
  }
  __syncthreads();

  const int part = tid & 3;
  const int grp = tid >> 2;
  const int zwr = (int)P.wr.z, zwz = (int)P.wz.z, zwn = (int)P.wn.z;
  const float swr = P.wr.s * P.rnn.s, swz = P.wz.s * P.rnn.s, swn = P.wn.s * P.rnn.s;
  // ring bases: [dir][slot][b][w], dir stride 12800, slot stride 3200
  unsigned long long* pubBase = hpub + (size_t)sl * 12800 + (size_t)b * 50;
  const unsigned long long* polBase = hpub + (size_t)(1 - sl) * 12800 + (size_t)b * 50;

  unsigned hcode = code0;
  unsigned pf = 0;

  for (int t = 0; t < 1000; ++t) {
    // ---- prefetch ace(t+1) (overlaps the poll) ----
    if (tid < 150) {
      int tn = (t + 1 < 1000) ? (t + 1) : 999;
      pf = *(const unsigned*)(psrc + ((size_t)tn * 64 + b) * 400 + poff);
    }
    // ---- wave 7: poll partner h(t), copy to hq, HqS, release flag ----
    if (tid >= 448) {
      int lane = tid - 448;
      unsigned pay = 0;
      if (lane < 50) {
        const unsigned long long* src = polBase + (size_t)(t & 3) * 3200 + lane;
        unsigned long long w64;
        while ((unsigned)((w64 = __hip_atomic_load(src, __ATOMIC_RELAXED, __HIP_MEMORY_SCOPE_AGENT)) >> 32)
               != (unsigned)t) { }
        pay = (unsigned)w64;
        int wd = (1 - sl) * 50 + lane;
        hq[t & 1][(wd / 25) * 28 + (wd % 25)] = pay;
      }
      if (lane == 0)
        __hip_atomic_store(&flag, t, __ATOMIC_RELEASE, __HIP_MEMORY_SCOPE_WORKGROUP);
      unsigned ssum = 0;
      if (lane < 50) {
        ssum = udot4_(pay, 0x01010101u, 0u);
        int wdo = sl * 50 + lane;
        unsigned own = hq[t & 1][(wdo / 25) * 28 + (wdo % 25)];
        ssum = udot4_(own, 0x01010101u, ssum);
      }
#pragma unroll
      for (int off = 32; off; off >>= 1) ssum += __shfl_down(ssum, off);
      if (lane == 0) HqS_s = (int)ssum;
    } else {
      while (__hip_atomic_load(&flag, __ATOMIC_ACQUIRE, __HIP_MEMORY_SCOPE_WORKGROUP) < t)
        __builtin_amdgcn_s_sleep(1);
    }
    // ---- phase D: dots ----
    const unsigned* hb = &hq[t & 1][part * 28];
    const unsigned* wl = &Wl[tid * 28];
    unsigned a0 = 0, a1 = 0, a2 = 0, a3 = 0, a4 = 0;
#pragma unroll
    for (int c = 0; c < 6; ++c) {
      uint4 h4 = *(const uint4*)(hb + 4 * c);
      a0 = udot4_(wq[0][4*c+0], h4.x, a0);
      a0 = udot4_(wq[0][4*c+1], h4.y, a0);
      a0 = udot4_(wq[0][4*c+2], h4.z, a0);
      a0 = udot4_(wq[0][4*c+3], h4.w, a0);
      a1 = udot4_(wq[1][4*c+0], h4.x, a1);
      a1 = udot4_(wq[1][4*c+1], h4.y, a1);
      a1 = udot4_(wq[1][4*c+2], h4.z, a1);
      a1 = udot4_(wq[1][4*c+3], h4.w, a1);
      a2 = udot4_(wq[2][4*c+0], h4.x, a2);
      a2 = udot4_(wq[2][4*c+1], h4.y, a2);
      a2 = udot4_(wq[2][4*c+2], h4.z, a2);
      a2 = udot4_(wq[2][4*c+3], h4.w, a2);
      a3 = udot4_(wq[3][4*c+0], h4.x, a3);
      a3 = udot4_(wq[3][4*c+1], h4.y, a3);
      a3 = udot4_(wq[3][4*c+2], h4.z, a3);
      a3 = udot4_(wq[3][4*c+3], h4.w, a3);
      if (tid < 352) {
        uint4 w4 = *(const uint4*)(wl + 4 * c);
        a4 = udot4_(w4.x, h4.x, a4);
        a4 = udot4_(w4.y, h4.y, a4);
        a4 = udot4_(w4.z, h4.z, a4);
        a4 = udot4_(w4.w, h4.w, a4);
      }
    }
    {
      unsigned hl = hb[24];
      a0 = udot4_(wq[0][24], hl, a0);
      a1 = udot4_(wq[1][24], hl, a1);
      a2 = udot4_(wq[2][24], hl, a2);
      a3 = udot4_(wq[3][24], hl, a3);
      if (tid < 352) a4 = udot4_(wl[24], hl, a4);
    }
    a0 += __shfl_xor(a0, 1); a0 += __shfl_xor(a0, 2);
    a1 += __shfl_xor(a1, 1); a1 += __shfl_xor(a1, 2);
    a2 += __shfl_xor(a2, 1); a2 += __shfl_xor(a2, 2);
    a3 += __shfl_xor(a3, 1); a3 += __shfl_xor(a3, 2);
    a4 += __shfl_xor(a4, 1); a4 += __shfl_xor(a4, 2);
    {
      int v = (part == 0) ? (int)a0 : (part == 1) ? (int)a1 : (part == 2) ? (int)a2 : (int)a3;
      dots_i[grp + 128 * part] = v;
      if (part == 0 && tid < 352) dots_i[512 + grp] = (int)a4;
    }
    __syncthreads();   // A: dots + HqS ready

    // ---- phase E: elementwise + repack + publish ----
    if (tid < 150) acew[(t + 1) & 1][tid] = pf;
    if (tid < 200) {
      const int j = tid;   // local j
      const unsigned char* ab = (const unsigned char*)&acew[t & 1][0];
      float av = ((float)ab[j]       - P.a.z) * P.a.s;
      float cv = ((float)ab[200 + j] - P.c.z) * P.c.s;
      float ev = ((float)ab[400 + j] - P.e.z) * P.e.s;
      int hqs = HqS_s;
      int Ib = dots_i[j]       - zwr * hqs + ic_l[j];
      int Id = dots_i[200 + j] - zwz * hqs + ic_l[200 + j];
      int If = dots_i[400 + j] - zwn * hqs + ic_l[400 + j];
      float bb = fq_((float)Ib * swr, P.b1.s, P.b1.z) + bias_l[j];
      bb = fq_(bb, P.b2.s, P.b2.z);
      float dd = fq_((float)Id * swz, P.d1.s, P.d1.z) + bias_l[200 + j];
      dd = fq_(dd, P.d2.s, P.d2.z);
      float ff = fq_((float)If * swn, P.f1.s, P.f1.z) + bias_l[400 + j];
      ff = fq_(ff, P.f2.s, P.f2.z);
      float r  = fq_(sigm_(fq_(av + bb, P.r1.s, P.r1.z)), P.r2.s, P.r2.z);
      float zz = fq_(sigm_(fq_(cv + dd, P.z1.s, P.z1.z)), P.z2.s, P.z2.z);
      float nn = fq_(tanhf(fq_(ev + fq_(r * ff, P.n1.s, P.n1.z), P.n2.s, P.n2.z)), P.n3.s, P.n3.z);
      float hold = ((float)hcode - P.rnn.z) * P.rnn.s;
      float hn2v = fq_(fq_(1.f - zz, P.hn1.s, P.hn1.z) * nn, P.hn2.s, P.hn2.z);
      float hn3v = fq_(zz * hold, P.hn3.s, P.hn3.z);
      float hnew = hn2v + hn3v;
      float qv = rintf(hnew / P.rnn.s) + P.rnn.z;
      qv = fminf(fmaxf(qv, 0.f), 255.f);
      unsigned code = (unsigned)qv;
      hcode = code;
      unsigned c1 = __shfl_down(code, 1);
      unsigned c2 = __shfl_down(code, 2);
      unsigned c3 = __shfl_down(code, 3);
      if ((j & 3) == 0) {
        unsigned packed = code | (c1 << 8) | (c2 << 16) | (c3 << 24);
        int wrd = j >> 2;                  // 0..49
        int wd = sl * 50 + wrd;            // global h word
        hq[(t + 1) & 1][(wd / 25) * 28 + (wd % 25)] = packed;
        *(unsigned*)(hs + ((size_t)t * 64 + b) * 400 + (wd << 2)) = packed;
        unsigned long long out64 = ((unsigned long long)(unsigned)(t + 1) << 32) | packed;
        __hip_atomic_store(pubBase + (size_t)((t + 1) & 3) * 3200 + wrd, out64,
                           __ATOMIC_RELAXED, __HIP_MEMORY_SCOPE_AGENT);
      }
    }
    __syncthreads();   // B: h(t+1) own half, ace(t+1) ready
  }
}

// ---------------- host launch ----------------
extern "C" void kernel_launch(void* const* d_in, const int* in_sizes, int n_in,
                              void* d_out, int out_size, void* d_ws, size_t ws_size,
                              hipStream_t stream)
{
  const float* x    = (const float*)d_in[0];
  const float* Wfc1 = (const float*)d_in[1];
  const float* bfc1 = (const float*)d_in[2];
  const float* Wiz1 = (const float*)d_in[3];  const float* Whz1 = (const float*)d_in[4];
  const float* biz1 = (const float*)d_in[5];  const float* bhz1 = (const float*)d_in[6];
  const float* Wir1 = (const float*)d_in[7];  const float* Whr1 = (const float*)d_in[8];
  const float* bir1 = (const float*)d_in[9];  const float* bhr1 = (const float*)d_in[10];
  const float* Win1 = (const float*)d_in[11]; const float* Whn1 = (const float*)d_in[12];
  const float* bin1 = (const float*)d_in[13]; const float* bhn1 = (const float*)d_in[14];
  const float* Wiz2 = (const float*)d_in[15]; const float* Whz2 = (const float*)d_in[16];
  const float* biz2 = (const float*)d_in[17]; const float* bhz2 = (const float*)d_in[18];
  const float* Wir2 = (const float*)d_in[19]; const float* Whr2 = (const float*)d_in[20];
  const float* bir2 = (const float*)d_in[21]; const float* bhr2 = (const float*)d_in[22];
  const float* Win2 = (const float*)d_in[23]; const float* Whn2 = (const float*)d_in[24];
  const float* bin2 = (const float*)d_in[25]; const float* bhn2 = (const float*)d_in[26];
  const float* Wfc2 = (const float*)d_in[27]; const float* bfc2 = (const float*)d_in[28];
  const float* Wfc3 = (const float*)d_in[29]; const float* bfc3 = (const float*)d_in[30];
  const float* Wfc4 = (const float*)d_in[31]; const float* bfc4 = (const float*)d_in[32];
  float* out = (float*)d_out;

  char* wp = (char*)d_ws;
  auto alloc = [&](size_t bytes) -> void* {
    void* p = (void*)wp;
    wp += (bytes + 255) & ~(size_t)255;
    return p;
  };
  float* b1q = (float*)alloc(400 * 4);
  float* biq = (float*)alloc(2400 * 4);
  float* bhq = (float*)alloc(2400 * 4);
  float* b2q = (float*)alloc(600 * 4);
  float* b3q = (float*)alloc(600 * 4);
  float* b4q = (float*)alloc(257 * 4);
  unsigned char* WhC = (unsigned char*)alloc(960000);
  int* colsum = (int*)alloc(2400 * 4);
  signed char* WiT = (signed char*)alloc(7 * 400 * 464);  // 6 proj + W1
  signed char* Bt2 = (signed char*)alloc(600 * 464);      // W2 (i8)
  bf16_t* Bt3 = (bf16_t*)alloc(600 * 608 * 2);            // W3 bf16 codes
  bf16_t* Bt4 = (bf16_t*)alloc(257 * 608 * 2);            // W4 bf16 codes
  int* cwi = (int*)alloc((7 * 400 + 600) * 4);
  int* rsX1 = (int*)alloc(64000 * 4);
  int* rsX  = (int*)alloc(64000 * 4);
  int* rsH  = (int*)alloc(64000 * 4);
  int* rsH2 = (int*)alloc(64000 * 4);
  unsigned char* xsq = (unsigned char*)alloc(25600000);
  unsigned char* Aq  = (unsigned char*)alloc(25600000);
  unsigned char* Cq  = (unsigned char*)alloc(25600000);
  unsigned char* Eq  = (unsigned char*)alloc(25600000);
  unsigned char* hs1 = (unsigned char*)alloc(25600000);
  unsigned char* hs2 = (unsigned char*)alloc(25600000);
  unsigned long long* hpub1 = (unsigned long long*)alloc(25600 * 8);
  unsigned long long* hpub2 = (unsigned long long*)alloc(25600 * 8);
  // overlays on dead regions
  float* y2c = (float*)Aq;                       // 38.4 MB (A/C/E dead during FC chain)
  float* y3c = (float*)(Aq + 38400000);          // 38.4 MB
  unsigned char* xcq = hs1;                      // x codes [64000][464] (hs1 dead pre-rec1)

  // ---- merged prep: all 16 bias fq in one launch ----
  BJobs bj;
  bj.j[0]  = { bfc1, b1q,        400, Zbfc1.s, Zbfc1.z };
  bj.j[1]  = { bir1, biq + 0,    400, Zbir1.s, Zbir1.z };
  bj.j[2]  = { biz1, biq + 400,  400, Zbiz1.s, Zbiz1.z };
  bj.j[3]  = { bin1, biq + 800,  400, Zbin1.s, Zbin1.z };
  bj.j[4]  = { bir2, biq + 1200, 400, Zbir2.s, Zbir2.z };
  bj.j[5]  = { biz2, biq + 1600, 400, Zbiz2.s, Zbiz2.z };
  bj.j[6]  = { bin2, biq + 2000, 400, Zbin2.s, Zbin2.z };
  bj.j[7]  = { bhr1, bhq + 0,    400, Zbhr1.s, Zbhr1.z };
  bj.j[8]  = { bhz1, bhq + 400,  400, Zbhz1.s, Zbhz1.z };
  bj.j[9]  = { bhn1, bhq + 800,  400, Zbhn1.s, Zbhn1.z };
  bj.j[10] = { bhr2, bhq + 1200, 400, Zbhr2.s, Zbhr2.z };
  bj.j[11] = { bhz2, bhq + 1600, 400, Zbhz2.s, Zbhz2.z };
  bj.j[12] = { bhn2, bhq + 2000, 400, Zbhn2.s, Zbhn2.z };
  bj.j[13] = { bfc2, b2q,        600, Zbfc2.s, Zbfc2.z };
  bj.j[14] = { bfc3, b3q,        600, Zbfc3.s, Zbfc3.z };
  bj.j[15] = { bfc4, b4q,        257, Zbfc4.s, Zbfc4.z };
  kbias<<<dim3(16), dim3(256), 0, stream>>>(bj);

  W6 wh = { { Whr1, Whz1, Whn1, Whr2, Whz2, Whn2 },
            { ZWhr1.s, ZWhz1.s, ZWhn1.s, ZWhr2.s, ZWhz2.s, ZWhn2.s },
            { ZWhr1.z, ZWhz1.z, ZWhn1.z, ZWhr2.z, ZWhz2.z, ZWhn2.z } };
  kwhc6<<<dim3(3750), dim3(256), 0, stream>>>(wh, WhC);
  kcolsum<<<dim3(10), dim3(256), 0, stream>>>(WhC, colsum);
  unsigned code0 = (unsigned)(Zrnn.z < 0.f ? 0.f : (Zrnn.z > 255.f ? 255.f : Zrnn.z));
  kinit2<<<dim3(100), dim3(256), 0, stream>>>(hpub1, hpub2, code0);

  hipMemsetAsync(cwi, 0, (7 * 400 + 600) * 4, stream);
  W6 wi = { { Wir1, Wiz1, Win1, Wir2, Wiz2, Win2 },
            { ZWir1.s, ZWiz1.s, ZWin1.s, ZWir2.s, ZWiz2.s, ZWin2.s },
            { ZWir1.z, ZWiz1.z, ZWin1.z, ZWir2.z, ZWiz2.z, ZWin2.z } };
  kwic6<<<dim3(625), dim3(256), 0, stream>>>(wi, WiT, cwi);
  kwic<<<dim3(625), dim3(256), 0, stream>>>(Wfc1, WiT + (size_t)6 * 185600, cwi + 2400, ZW1.s, ZW1.z, 257, 400);
  kwic<<<dim3(625), dim3(256), 0, stream>>>(Wfc2, Bt2, cwi + 2800, ZWfc2.s, ZWfc2.z, 400, 600);
  kwbf<<<dim3(625), dim3(256), 0, stream>>>(Wfc3, Bt3, ZWfc3.s, ZWfc3.z, 600, 600);
  kwbf<<<dim3(625), dim3(256), 0, stream>>>(Wfc4, Bt4, ZWfc4.s, ZWfc4.z, 600, 257);

  auto gi8 = [&](const unsigned char* A, int strideA, int aw4, const int* rs,
                 const signed char* Bt, const int* cs, const float* bias,
                 unsigned char* oU8, float* oF, int M, int N, int outStride, int epMode,
                 SZ a, SZ w, int Kreal, float ss, SZ e1, SZ e2) {
    int czw = 128 - (int)w.z, cza = 128 - (int)a.z;
    int cconst = Kreal * cza * czw;
    int nb = (N + 79) / 80;
    gemm_i8<<<dim3((M / 64) * nb), dim3(256), 0, stream>>>(
        A, strideA, aw4, rs, Bt, cs, bias, oU8, oF, N, nb, outStride, epMode,
        czw, cza, cconst, ss, e1.s, e1.z, e2.s, e2.z);
  };

  // ---- FC1 (exact-int i8): x codes -> xsq codes ----
  kxq<<<dim3((64000 * 464 + 255) / 256), dim3(256), 0, stream>>>(x, xcq, Zx.s, Zx.z);
  krsum<<<dim3(250), dim3(256), 0, stream>>>(xcq, rsX1, 29);
  gi8(xcq, 464, 29, rsX1, WiT + (size_t)6 * 185600, cwi + 2400, b1q,
      xsq, nullptr, 64000, 400, 400, 0, Zx, ZW1, 257, Zx.s * ZW1.s, Zfc1mm, Zfc1add);

  // ---- GRU layer 1 input projections (i8) ----
  krsum<<<dim3(250), dim3(256), 0, stream>>>(xsq, rsX, 25);
  gi8(xsq, 400, 25, rsX, WiT + (size_t)0 * 185600, cwi + 0,    biq + 0,   Aq, nullptr,
      64000, 400, 400, 0, Zfc1add, ZWir1, 400, Zfc1add.s * ZWir1.s, Za_1, Za1);
  gi8(xsq, 400, 25, rsX, WiT + (size_t)1 * 185600, cwi + 400,  biq + 400, Cq, nullptr,
      64000, 400, 400, 0, Zfc1add, ZWiz1, 400, Zfc1add.s * ZWiz1.s, Zc_1, Zc1);
  gi8(xsq, 400, 25, rsX, WiT + (size_t)2 * 185600, cwi + 800,  biq + 800, Eq, nullptr,
      64000, 400, 400, 0, Zfc1add, ZWin1, 400, Zfc1add.s * ZWin1.s, Ze_1, Ze1);
  // ---- GRU layer 1 recurrence (2 blocks per batch) ----
  gru_rec2b<<<dim3(128), dim3(512), 0, stream>>>(WhC, colsum, Aq, Cq, Eq,
                                                 bhq + 0, bhq + 400, bhq + 800,
                                                 hs1, hpub1, PL1);
  // ---- GRU layer 2 input projections (i8) ----
  krsum<<<dim3(250), dim3(256), 0, stream>>>(hs1, rsH, 25);
  gi8(hs1, 400, 25, rsH, WiT + (size_t)3 * 185600, cwi + 1200, biq + 1200, Aq, nullptr,
      64000, 400, 400, 0, Zrnn, ZWir2, 400, Zrnn.s * ZWir2.s, Za_2, Za2);
  gi8(hs1, 400, 25, rsH, WiT + (size_t)4 * 185600, cwi + 1600, biq + 1600, Cq, nullptr,
      64000, 400, 400, 0, Zrnn, ZWiz2, 400, Zrnn.s * ZWiz2.s, Zc_2, Zc2);
  gi8(hs1, 400, 25, rsH, WiT + (size_t)5 * 185600, cwi + 2000, biq + 2000, Eq, nullptr,
      64000, 400, 400, 0, Zrnn, ZWin2, 400, Zrnn.s * ZWin2.s, Ze_2, Ze1);
  // ---- GRU layer 2 recurrence ----
  gru_rec2b<<<dim3(128), dim3(512), 0, stream>>>(WhC + 480000, colsum + 1200, Aq, Cq, Eq,
                                                 bhq + 1200, bhq + 1600, bhq + 2000,
                                                 hs2, hpub2, PL2);
  // ---- FC2 (i8) -> FC3 -> FC4 (bf16x2 MFMA) in 4 row chunks ----
  krsum<<<dim3(250), dim3(256), 0, stream>>>(hs2, rsH2, 25);
  for (int rc = 0; rc < 4; ++rc) {
    const unsigned char* a2 = hs2 + (size_t)rc * 16000 * 400;
    gi8(a2, 400, 25, rsH2 + rc * 16000, Bt2, cwi + 2800, b2q, nullptr, y2c,
        16000, 600, 600, 2, Zrnn, ZWfc2, 400, Zrnn.s * ZWfc2.s, Zrnn, Zrnn);
    gemm_bf<<<dim3(125 * 5), dim3(512), 0, stream>>>(y2c, Bt3, b3q, y3c, 600, 5, 2, 0, ZWfc3.s);
    gemm_bf<<<dim3(125 * 3), dim3(512), 0, stream>>>(y3c, Bt4, b4q, out, 257, 3, 3, rc * 16000, ZWfc4.s);
  }
  (void)in_sizes; (void)n_in; (void)out_size; (void)ws_size;
}

// Round 5
// 6831.296 us; speedup vs baseline: 1.7902x; 1.0027x over previous
//
#include <hip/hip_runtime.h>
#include <math.h>

#define DEV static __device__ __forceinline__

typedef int v4i __attribute__((ext_vector_type(4)));
typedef float v4f __attribute__((ext_vector_type(4)));
typedef __bf16 bf16_t;
typedef __bf16 v8bf __attribute__((ext_vector_type(8)));

// ---------------- calibration (s, z) constants, computed like the reference ----------------
struct SZ { float s, z; };

constexpr double cfloor_(double v){ long long i=(long long)v; return ((double)i > v) ? (double)(i-1) : (double)i; }
constexpr double cround_(double v){            // round half-to-even (Python round / nearbyint)
  double fl = cfloor_(v); double fr = v - fl;
  return (fr > 0.5) ? fl + 1.0 : (fr < 0.5 ? fl : ((((long long)fl) & 1LL) == 0 ? fl : fl + 1.0));
}
constexpr SZ mksz(double mn, double mx){
  double s = (mx - mn) / 255.0;
  double z = cround_(-mn / s);
  return SZ{ (float)s, (float)z };
}

constexpr SZ Zx     = mksz(-0.0025095, 0.0022181);
constexpr SZ ZW1    = mksz(-0.22075387835502625, 0.208940327167511);
constexpr SZ Zfc1mm = mksz(-0.00291599917, 0.0017367251);
constexpr SZ Zbfc1  = mksz(-0.48688140511512756, 0.5176185369491577);
constexpr SZ Zfc1add= mksz(-0.48778465390205383, 0.5181604027748108);
// layer-1 weights/biases
constexpr SZ ZWiz1 = mksz(-0.43284985423088074, 0.46175122261047363);
constexpr SZ ZWir1 = mksz(-0.34401071071624756, 0.29191476106643677);
constexpr SZ ZWin1 = mksz(-0.3236880302429199, 0.39607325196266174);
constexpr SZ ZWhz1 = mksz(-1.8417714834213257, 1.7173254489898682);
constexpr SZ ZWhr1 = mksz(-1.1574513912200928, 1.0300449132919312);
constexpr SZ ZWhn1 = mksz(-0.7756922245025635, 0.9530389308929443);
constexpr SZ Zbiz1 = mksz(-0.5063393712043762, 0.36664387583732605);
constexpr SZ Zbir1 = mksz(-0.07920225709676743, 0.20611026883125305);
constexpr SZ Zbin1 = mksz(-0.5539973378181458, 0.17938342690467834);
constexpr SZ Zbhz1 = mksz(-0.5337516665458679, 0.4148772358894348);
constexpr SZ Zbhr1 = mksz(-0.07688436657190323, 0.14814253151416779);
constexpr SZ Zbhn1 = mksz(-0.7828555107116699, 0.9008108973503113);
// layer-2 weights/biases
constexpr SZ ZWiz2 = mksz(-0.9102030992507935, 0.9408696889877319);
constexpr SZ ZWir2 = mksz(-0.9560997486114502, 0.6683358550071716);
constexpr SZ ZWin2 = mksz(-0.4721935987472534, 0.48561596870422363);
constexpr SZ ZWhz2 = mksz(-1.2992678880691528, 1.2991048097610474);
constexpr SZ ZWhr2 = mksz(-0.8318714499473572, 1.1085889339447021);
constexpr SZ ZWhn2 = mksz(-0.955470085144043, 1.046797513961792);
constexpr SZ Zbiz2 = mksz(-0.44805487990379333, 0.1560053527355194);
constexpr SZ Zbir2 = mksz(-0.08767592161893845, 0.11347303539514542);
constexpr SZ Zbin2 = mksz(-0.239909827709198, 0.12033259868621826);
constexpr SZ Zbhz2 = mksz(-0.43745461106300354, 0.12699371576309204);
constexpr SZ Zbhr2 = mksz(-0.09617264568805695, 0.07690174877643585);
constexpr SZ Zbhn2 = mksz(-0.17204178869724274, 0.19739042222499847);
// fc tail
constexpr SZ ZWfc2 = mksz(-1.3657219409942627, 1.158295750617981);
constexpr SZ Zbfc2 = mksz(-0.1750922054052353, 0.1385071724653244);
constexpr SZ ZWfc3 = mksz(-3.1666038036346436, 2.5026357173919678);
constexpr SZ Zbfc3 = mksz(-0.10188056528568268, 0.0899151861667633);
constexpr SZ ZWfc4 = mksz(-1.300571084022522, 1.928941249847412);
constexpr SZ Zbfc4 = mksz(-0.10699586570262909, 0.04597663879394531);
// gru1 stages
constexpr SZ Za_1 = mksz(-0.6389939785003662, 0.7715625762939453);
constexpr SZ Za1  = mksz(-0.6046768426895142, 0.8871182203292847);
constexpr SZ Zb_1 = mksz(-0.004922409541904926, 0.004103424027562141);
constexpr SZ Zb1  = mksz(-0.07475128024816513, 0.14630259573459625);
constexpr SZ Zc_1 = mksz(-1.5660111904144287, 1.0454494953155518);
constexpr SZ Zc1  = mksz(-1.9779117107391357, 1.3700535297393799);
constexpr SZ Zd_1 = mksz(-0.008429044857621193, 0.006403823848813772);
constexpr SZ Zd1  = mksz(-0.5529640316963196, 0.41507571935653687);
constexpr SZ Ze_1 = mksz(-1.3637111186981201, 1.018247127532959);
constexpr SZ Ze1  = mksz(-1.8583884239196777, 1.1587692499160767);
constexpr SZ Zf_1 = mksz(-0.005411399528384209, 0.0061536869034171104);
constexpr SZ Zf1  = mksz(-0.7833794355392456, 0.8978855013847351);
constexpr SZ Zr_1 = mksz(-0.6226556301116943, 0.9800534844398499);
constexpr SZ Zr1  = mksz(0.3491777181625366, 0.7271188497543335);
constexpr SZ Zz_1 = mksz(-2.392332077026367, 1.7851293087005615);
constexpr SZ Zz1  = mksz(0.08375928550958633, 0.856329083442688);
constexpr SZ Zn11 = mksz(-0.5516456365585327, 0.4556601643562317);
constexpr SZ Zn21 = mksz(-2.4100341796875, 1.1423156261444092);
constexpr SZ Zn1  = mksz(-0.983996570110321, 0.8151924014091492);
constexpr SZ Zhn11= mksz(0.143670916557312, 0.9162406921386719);
constexpr SZ Zhn21= mksz(-0.9015777111053467, 0.45391541719436646);
constexpr SZ Zhn31= mksz(-0.0016954239690676332, 0.0016671211924403906);
constexpr SZ Zrnn = mksz(-0.9016271829605103, 0.4546271562576294);
// gru2 explicit entries (the rest fall back to gru1 values, incl. rnn2GRU)
constexpr SZ Za_2 = mksz(-0.681461751461029, 0.9113116264343262);
constexpr SZ Za2  = mksz(-0.7149235010147095, 0.908741295337677);
constexpr SZ Zb_2 = mksz(-0.005148397758603096, 0.011014967225492);
constexpr SZ Zb2g = mksz(-0.09436552226543427, 0.07623167335987091);
constexpr SZ Zc_2 = mksz(-1.2279887199401855, 1.1102137565612793);
constexpr SZ Zc2  = mksz(-1.6760436296463013, 1.200895071029663);
constexpr SZ Zd_2 = mksz(-0.008141756057739258, 0.00894666276872158);
constexpr SZ Zd2  = mksz(-0.43875735998153687, 0.1262134611606598);
constexpr SZ Ze_2 = mksz(-0.6732944250106812, 0.6314664483070374);

struct RecP {
  SZ wr, wz, wn;
  SZ a, c, e;
  SZ b1, b2, d1, d2, f1, f2;
  SZ r1, r2, z1, z2;
  SZ n1, n2, n3;
  SZ hn1, hn2, hn3, rnn;
};
constexpr RecP PL1 = { ZWhr1, ZWhz1, ZWhn1, Za1, Zc1, Ze1, Zb_1, Zb1, Zd_1, Zd1, Zf_1, Zf1,
                       Zr_1, Zr1, Zz_1, Zz1, Zn11, Zn21, Zn1, Zhn11, Zhn21, Zhn31, Zrnn };
constexpr RecP PL2 = { ZWhr2, ZWhz2, ZWhn2, Za2, Zc2, Ze1, Zb_2, Zb2g, Zd_2, Zd2, Zf_1, Zf1,
                       Zr_1, Zr1, Zz_1, Zz1, Zn11, Zn21, Zn1, Zhn11, Zhn21, Zhn31, Zrnn };

// ---------------- device helpers ----------------
DEV float fq_(float x, float s, float z){
  float q = rintf(x / s) + z;
  q = fminf(fmaxf(q, 0.f), 255.f);
  return (q - z) * s;
}
DEV float sigm_(float v){ return 1.f / (1.f + expf(-v)); }

DEV unsigned udot4_(unsigned a, unsigned b, unsigned c){
#if defined(__has_builtin) && __has_builtin(__builtin_amdgcn_udot4)
  return __builtin_amdgcn_udot4(a, b, c, false);
#else
  return c + (a & 255u) * (b & 255u) + ((a >> 8) & 255u) * ((b >> 8) & 255u)
           + ((a >> 16) & 255u) * ((b >> 16) & 255u) + (a >> 24) * (b >> 24);
#endif
}

// ---------------- prep kernels ----------------
struct BJob { const float* src; float* dst; int n; float s; float z; };
struct BJobs { BJob j[16]; };
__global__ __launch_bounds__(256) void kbias(BJobs jobs){
  BJob J = jobs.j[blockIdx.x];
  for (int i = threadIdx.x; i < J.n; i += 256) J.dst[i] = fq_(J.src[i], J.s, J.z);
}

struct W6 { const float* W[6]; float s[6]; float z[6]; };
// six Wh [400][400] (k-major) -> u8 codes, column-major [m][j][k]
__global__ __launch_bounds__(256) void kwhc6(W6 jb, unsigned char* __restrict__ dst){
  int i = blockIdx.x * 256 + threadIdx.x;
  if (i < 960000) {
    int m = i / 160000, r = i - m * 160000;
    int j = r / 400, k = r - j * 400;
    float q = rintf(jb.W[m][k * 400 + j] / jb.s[m]) + jb.z[m];
    q = fminf(fmaxf(q, 0.f), 255.f);
    dst[i] = (unsigned char)q;
  }
}
__global__ __launch_bounds__(256) void kcolsum(const unsigned char* __restrict__ WhC, int* __restrict__ cs){
  int i = blockIdx.x * 256 + threadIdx.x;
  if (i < 2400) {
    const unsigned char* p = WhC + (size_t)i * 400;
    int s = 0;
    for (int k = 0; k < 400; ++k) s += p[k];
    cs[i] = s;
  }
}
// six Wi [400][400] -> transposed biased codes [m][n][464] + colsum(q-128)
__global__ __launch_bounds__(256) void kwic6(W6 jb, signed char* __restrict__ WiT, int* __restrict__ cs){
  for (int idx = blockIdx.x * 256 + threadIdx.x; idx < 960000; idx += gridDim.x * 256) {
    int m = idx / 160000, r = idx - m * 160000;
    int k = r / 400, n = r - k * 400;
    float q = rintf(jb.W[m][r] / jb.s[m]) + jb.z[m];
    q = fminf(fmaxf(q, 0.f), 255.f);
    int qi = (int)q;
    WiT[(size_t)m * 185600 + (size_t)n * 464 + k] = (signed char)(qi ^ 0x80);
    atomicAdd(&cs[m * 400 + n], qi - 128);
  }
  for (int idx = blockIdx.x * 256 + threadIdx.x; idx < 153600; idx += gridDim.x * 256) {
    int m = idx / 25600, r = idx - m * 25600;
    int n = r / 64, p = r - n * 64;
    WiT[(size_t)m * 185600 + (size_t)n * 464 + 400 + p] = 0;
  }
}
// W [K][N] f32 -> transposed biased codes Bt [N][464] + colsum(q-128)  (FC1/FC2)
__global__ __launch_bounds__(256) void kwic(const float* __restrict__ W, signed char* __restrict__ Bt,
                                            int* __restrict__ cs, float s, float z, int K, int N){
  int total1 = K * N, total2 = (464 - K) * N;
  for (int idx = blockIdx.x * 256 + threadIdx.x; idx < total1; idx += gridDim.x * 256) {
    int k = idx / N, n = idx - k * N;
    float q = rintf(W[idx] / s) + z;
    q = fminf(fmaxf(q, 0.f), 255.f);
    int qi = (int)q;
    Bt[(size_t)n * 464 + k] = (signed char)(qi ^ 0x80);
    atomicAdd(&cs[n], qi - 128);
  }
  for (int idx = blockIdx.x * 256 + threadIdx.x; idx < total2; idx += gridDim.x * 256) {
    int n = idx / (464 - K), k = K + (idx - n * (464 - K));
    Bt[(size_t)n * 464 + k] = 0;
  }
}
// W [K][N] f32 -> transposed bf16 INTEGER codes (q-z) in [N][608] (pad 0)  (FC3/FC4)
__global__ __launch_bounds__(256) void kwbf(const float* __restrict__ W, bf16_t* __restrict__ Bt,
                                            float s, float z, int K, int N){
  int total1 = K * N, total2 = (608 - K) * N;
  for (int idx = blockIdx.x * 256 + threadIdx.x; idx < total1; idx += gridDim.x * 256) {
    int k = idx / N, n = idx - k * N;
    float q = rintf(W[idx] / s) + z;
    q = fminf(fmaxf(q, 0.f), 255.f);
    Bt[(size_t)n * 608 + k] = (bf16_t)(q - z);     // integer in [-255,255]: exact in bf16
  }
  for (int idx = blockIdx.x * 256 + threadIdx.x; idx < total2; idx += gridDim.x * 256) {
    int n = idx / (608 - K), k = K + (idx - n * (608 - K));
    Bt[(size_t)n * 608 + k] = (bf16_t)0.f;
  }
}
// quantize x [B,T,F] -> xcq codes [T*64+b][464] (pads = code 128)
__global__ __launch_bounds__(256) void kxq(const float* __restrict__ x, unsigned char* __restrict__ xcq,
                                           float s, float z){
  int idx = blockIdx.x * 256 + threadIdx.x;
  if (idx < 64000 * 464) {
    int row = idx / 464, c = idx - row * 464;
    unsigned char code = 128;
    if (c < 257) {
      int bb = row & 63, tt = row >> 6;
      float q = rintf(x[((size_t)bb * 1000 + tt) * 257 + c] / s) + z;
      q = fminf(fmaxf(q, 0.f), 255.f);
      code = (unsigned char)q;
    }
    xcq[idx] = code;
  }
}
// per-row sums of (q-128) over w4 uint4-words of u8 codes (pads must be code 128)
__global__ __launch_bounds__(256) void krsum(const unsigned char* __restrict__ A, int* __restrict__ rs,
                                             int w4){
  int r = blockIdx.x * 256 + threadIdx.x;
  const unsigned* p = (const unsigned*)(A + (size_t)r * (w4 * 16));
  unsigned s = 0;
  for (int i = 0; i < w4 * 4; ++i) s = udot4_(p[i], 0x01010101u, s);
  rs[r] = (int)s - 128 * 4 * (w4 * 4);
}
// init all 4 ring slots of both layers with tag-0 code0 payloads
__global__ __launch_bounds__(256) void kinit2(unsigned long long* __restrict__ hp1,
                                              unsigned long long* __restrict__ hp2, unsigned code){
  int i = blockIdx.x * 256 + threadIdx.x;
  if (i < 25600) {
    unsigned long long w = (unsigned long long)(code * 0x01010101u);
    hp1[i] = w; hp2[i] = w;
  }
}

// ---------------- exact-int i8 MFMA GEMM ----------------
// BM=64, BN=80, K padded to 448. dot_int = S + czw*RA' + cza*CW' + cconst.
__global__ __launch_bounds__(256) void gemm_i8(
    const unsigned char* __restrict__ Au8, int strideA, int aw4,
    const int* __restrict__ rowsum,
    const signed char* __restrict__ Bt, const int* __restrict__ colsum,
    const float* __restrict__ bias,
    unsigned char* __restrict__ outU8, float* __restrict__ outF,
    int N, int nb, int outStride, int epMode,
    int czw, int cza, int cconst, float ss,
    float e1S, float e1Z, float e2S, float e2Z)
{
  __shared__ __align__(16) signed char Asl[64 * 464];
  __shared__ __align__(16) signed char Bsl[80 * 464];
  const int tid = threadIdx.x;
  const int bm = blockIdx.x / nb;
  const int bn = blockIdx.x - bm * nb;
  const int m0 = bm * 64;
  const int n0 = bn * 80;
  for (int i = tid; i < 80 * 29; i += 256) {
    int r = i / 29, c = i - r * 29;
    uint4 v;
    if (n0 + r < N) v = *(const uint4*)(Bt + (size_t)(n0 + r) * 464 + c * 16);
    else { v.x = 0u; v.y = 0u; v.z = 0u; v.w = 0u; }
    *(uint4*)(Bsl + (size_t)r * 464 + c * 16) = v;
  }
  for (int i = tid; i < 64 * 29; i += 256) {
    int r = i / 29, c = i - r * 29;
    uint4 v;
    if (c < aw4) {
      v = *(const uint4*)(Au8 + (size_t)(m0 + r) * strideA + c * 16);
      v.x ^= 0x80808080u; v.y ^= 0x80808080u; v.z ^= 0x80808080u; v.w ^= 0x80808080u;
    } else { v.x = 0u; v.y = 0u; v.z = 0u; v.w = 0u; }
    *(uint4*)(Asl + (size_t)r * 464 + c * 16) = v;
  }
  __syncthreads();
  const int wv = tid >> 6, ln = tid & 63;
  const int lr = ln & 15;
  const int lk = ln >> 4;
  v4i acc[5];
#pragma unroll
  for (int j = 0; j < 5; ++j) { acc[j][0] = 0; acc[j][1] = 0; acc[j][2] = 0; acc[j][3] = 0; }
#pragma unroll
  for (int kc = 0; kc < 7; ++kc) {
    int kb = kc * 64 + lk * 16;
    v4i a = *(const v4i*)(Asl + (size_t)(wv * 16 + lr) * 464 + kb);
#pragma unroll
    for (int j = 0; j < 5; ++j) {
      v4i b = *(const v4i*)(Bsl + (size_t)(j * 16 + lr) * 464 + kb);
      acc[j] = __builtin_amdgcn_mfma_i32_16x16x64_i8(a, b, acc[j], 0, 0, 0);
    }
  }
#pragma unroll
  for (int reg = 0; reg < 4; ++reg) {
    int row = m0 + wv * 16 + lk * 4 + reg;
    int RA = rowsum[row];
#pragma unroll
    for (int j = 0; j < 5; ++j) {
      int col = n0 + j * 16 + lr;
      if (col >= N) continue;
      int I = acc[j][reg] + czw * RA + cza * colsum[col] + cconst;
      float v = (float)I * ss;
      if (epMode == 0) {
        v = fq_(v, e1S, e1Z) + bias[col];
        float q = rintf(v / e2S) + e2Z;
        q = fminf(fmaxf(q, 0.f), 255.f);
        outU8[(size_t)row * outStride + col] = (unsigned char)q;
      } else {
        v += bias[col];
        v = fmaxf(v, 0.f);
        outF[(size_t)row * outStride + col] = v;
      }
    }
  }
}

// ---------------- bf16x2-split MFMA GEMM (FC3/FC4) ----------------
__global__ __launch_bounds__(512) void gemm_bf(
    const float* __restrict__ A, const bf16_t* __restrict__ Bt,
    const float* __restrict__ bias, float* __restrict__ outF,
    int N, int nb, int epMode, int rowOff, float sc)
{
  __shared__ __align__(16) bf16_t Bs[128 * 616];   // row stride 616 (conflict-free b128)
  const int tid = threadIdx.x;
  const int bm = blockIdx.x / nb;
  const int bn = blockIdx.x - bm * nb;
  const int m0 = bm * 128;
  const int n0 = bn * 128;
  for (int i = tid; i < 128 * 76; i += 512) {
    int r = i / 76, c = i - r * 76;
    uint4 v; v.x = 0u; v.y = 0u; v.z = 0u; v.w = 0u;
    if (n0 + r < N) v = *(const uint4*)((const char*)(Bt + (size_t)(n0 + r) * 608) + c * 16);
    *(uint4*)((char*)(Bs + (size_t)r * 616) + c * 16) = v;
  }
  __syncthreads();
  const int wv = tid >> 6, ln = tid & 63;
  const int lr = ln & 15, quad = ln >> 4;
  const float* arp = A + (size_t)(m0 + wv * 16 + lr) * 600;
  v4f acc[8];
#pragma unroll
  for (int j = 0; j < 8; ++j) { acc[j][0] = 0.f; acc[j][1] = 0.f; acc[j][2] = 0.f; acc[j][3] = 0.f; }
  for (int kc = 0; kc < 19; ++kc) {
    int kb = kc * 32 + quad * 8;
    float af[8];
    if (kc == 18 && quad == 3) {
#pragma unroll
      for (int j = 0; j < 8; ++j) af[j] = 0.f;
    } else {
      *(float4*)&af[0] = *(const float4*)(arp + kb);
      *(float4*)&af[4] = *(const float4*)(arp + kb + 4);
    }
    v8bf ah, al;
#pragma unroll
    for (int j = 0; j < 8; ++j) {
      float xx = af[j];
      bf16_t h = (bf16_t)xx;
      ah[j] = h;
      al[j] = (bf16_t)(xx - (float)h);
    }
#pragma unroll
    for (int nf = 0; nf < 8; ++nf) {
      v8bf bfrag = *(const v8bf*)(Bs + (size_t)(nf * 16 + lr) * 616 + kc * 32 + quad * 8);
      acc[nf] = __builtin_amdgcn_mfma_f32_16x16x32_bf16(ah, bfrag, acc[nf], 0, 0, 0);
      acc[nf] = __builtin_amdgcn_mfma_f32_16x16x32_bf16(al, bfrag, acc[nf], 0, 0, 0);
    }
  }
#pragma unroll
  for (int nf = 0; nf < 8; ++nf) {
    int col = n0 + nf * 16 + lr;
    if (col >= N) continue;
    float bcol = bias[col];
#pragma unroll
    for (int reg = 0; reg < 4; ++reg) {
      int row = m0 + wv * 16 + quad * 4 + reg;
      float v = acc[nf][reg] * sc + bcol;
      if (epMode == 2) {
        v = fmaxf(v, 0.f);
        outF[(size_t)row * N + col] = v;
      } else {
        v = sigm_(v);
        int rg = rowOff + row;
        int tt = rg >> 6, bb = rg & 63;
        outF[((size_t)bb * 1000 + tt) * 257 + col] = v;
      }
    }
  }
}

// ---------------- GRU recurrence: 4 blocks/batch, weights in 50 VGPRs + 20KB LDS ----------------
// 256 blocks x 512 threads (1 block/CU; partner blocks b, b+64, b+128, b+192 share an XCD
// since 64 % 8 == 0). Block (sl, b): sl = blockIdx>>6 in 0..3, b = blockIdx&63.
// Each block owns j in [sl*100, sl*100+100) for all 3 gates: 300 dots x 4 k-quarters =
// 1200 quarter-slots. Slot q = tid + 512*s for s=0,1 in REGISTERS (wq[2][25] = 50 VGPRs,
// sized for the ~88-VGPR budget the RA actually allocates -- R1/R2/R4 showed bigger
// arrays always spill), slots q = 1024+tid (tid<176) in LDS (19.7 KB). part (q&3) ==
// (tid&3): fixed 25-word h k-slice/thread; quad butterfly completes dots. Per step each
// block publishes its 25 h-words to a depth-4 tagged ring and wave 7 polls the 3
// partners' 75 words (R0's proven scheme), copies to LDS, computes HqS, releases an
// LDS flag (spinners: plain acquire spin, no s_sleep).
__global__ __launch_bounds__(512) void gru_rec4b(
    const unsigned char* __restrict__ WhC, const int* __restrict__ colsum,
    const unsigned char* __restrict__ Aq, const unsigned char* __restrict__ Cq,
    const unsigned char* __restrict__ Eq,
    const float* __restrict__ bhr, const float* __restrict__ bhz, const float* __restrict__ bhn,
    unsigned char* __restrict__ hs, unsigned long long* __restrict__ hpub, RecP P)
{
  __shared__ __align__(16) unsigned Wl[176 * 28];   // 19,712 B LDS quarter-slots
  __shared__ __align__(16) unsigned hq[2][4 * 28];  // h codes, [part][25 words] stride 28
  __shared__ int dots_i[300];
  __shared__ unsigned acew[2][75];                  // own-j a/c/e codes (3 gates x 25 words)
  __shared__ int ic_l[300];
  __shared__ float bias_l[300];
  __shared__ int HqS_s;
  __shared__ int flag;

  const int tid = threadIdx.x;
  const int sl = blockIdx.x >> 6;
  const int b  = blockIdx.x & 63;
  const unsigned* Wu = (const unsigned*)WhC;

  // ---- register-resident weight quarters (2 x 25 dwords = 50 VGPRs) ----
  unsigned wq[2][25];
#pragma unroll
  for (int s = 0; s < 2; ++s) {
    int q = tid + 512 * s;
    int ld = q >> 2, p = q & 3;
    int g = ld / 100, jl = ld - g * 100;
    int col = g * 400 + sl * 100 + jl;
    const unsigned* src = Wu + col * 100 + p * 25;
#pragma unroll
    for (int w = 0; w < 25; ++w) wq[s][w] = src[w];
  }
  // ---- LDS weight quarters: q = 1024 + tid (tid < 176), ld in [256,300) ----
  if (tid < 176) {
    int q = 1024 + tid;
    int ld = q >> 2, p = q & 3;
    int g = ld / 100, jl = ld - g * 100;
    int col = g * 400 + sl * 100 + jl;
    const unsigned* src = Wu + col * 100 + p * 25;
    for (int w = 0; w < 25; ++w) Wl[tid * 28 + w] = src[w];
  }
  // ---- per-dot correction + bias tables (local dot ld = g*100 + jl) ----
  const int zh = (int)P.rnn.z;
  if (tid < 300) {
    int ld = tid;
    int g = ld / 100, jl = ld - g * 100;
    int col = g * 400 + sl * 100 + jl;
    int zw = (g == 0) ? (int)P.wr.z : (g == 1) ? (int)P.wz.z : (int)P.wn.z;
    ic_l[ld] = -zh * colsum[col] + 400 * zh * zw;
    bias_l[ld] = ((g == 0) ? bhr : (g == 1) ? bhz : bhn)[sl * 100 + jl];
  }
  // ---- h0 / ace(t=0) / flag init ----
  const unsigned code0 = (unsigned)fminf(fmaxf(P.rnn.z, 0.f), 255.f);
  for (int i = tid; i < 100; i += 512)
    hq[0][(i / 25) * 28 + (i % 25)] = code0 * 0x01010101u;
  if (tid == 0) flag = -1;
  const unsigned char* psrc = nullptr;
  int poff = 0;
  if (tid < 75) {
    int g = tid / 25, w = tid - g * 25;
    psrc = (g == 0) ? Aq : (g == 1) ? Cq : Eq;
    poff = (sl * 25 + w) * 4;
    acew[0][tid] = *(const unsigned*)(psrc + (size_t)b * 400 + poff);
  }
  __syncthreads();

  const int part = tid & 3;
  const int grp = tid >> 2;
  const int zwr = (int)P.wr.z, zwz = (int)P.wz.z, zwn = (int)P.wn.z;
  const float swr = P.wr.s * P.rnn.s, swz = P.wz.s * P.rnn.s, swn = P.wn.s * P.rnn.s;

  unsigned hcode = code0;
  unsigned pf = 0;

  for (int t = 0; t < 1000; ++t) {
    // ---- prefetch ace(t+1) (overlaps the poll) ----
    if (tid < 75) {
      int tn = (t + 1 < 1000) ? (t + 1) : 999;
      pf = *(const unsigned*)(psrc + ((size_t)tn * 64 + b) * 400 + poff);
    }
    // ---- wave 7: poll 3 partners' h(t), copy to hq, release flag, HqS ----
    if (tid >= 448) {
      int lane = tid - 448;
      const unsigned long long* base = hpub + ((size_t)(t & 3) * 64 + b) * 100;
      unsigned pay0, pay1 = 0;
      {
        int o = lane / 25, p = lane - o * 25;           // lane 0..63 -> o in 0..2
        int so = (sl + o + 1) & 3;
        const unsigned long long* src = base + so * 25 + p;
        unsigned long long w64;
        while ((unsigned)((w64 = __hip_atomic_load(src, __ATOMIC_RELAXED, __HIP_MEMORY_SCOPE_AGENT)) >> 32)
               != (unsigned)t) { }
        pay0 = (unsigned)w64;
        hq[t & 1][so * 28 + p] = pay0;
      }
      if (lane < 11) {
        int w1 = 64 + lane;
        int o = w1 / 25, p = w1 - o * 25;               // o == 2
        int so = (sl + o + 1) & 3;
        const unsigned long long* src = base + so * 25 + p;
        unsigned long long w64;
        while ((unsigned)((w64 = __hip_atomic_load(src, __ATOMIC_RELAXED, __HIP_MEMORY_SCOPE_AGENT)) >> 32)
               != (unsigned)t) { }
        pay1 = (unsigned)w64;
        hq[t & 1][so * 28 + p] = pay1;
      }
      if (lane == 0)
        __hip_atomic_store(&flag, t, __ATOMIC_RELEASE, __HIP_MEMORY_SCOPE_WORKGROUP);
      unsigned ssum = udot4_(pay0, 0x01010101u, 0u);
      if (lane < 11) ssum = udot4_(pay1, 0x01010101u, ssum);
      if (lane < 25) ssum = udot4_(hq[t & 1][sl * 28 + lane], 0x01010101u, ssum);
#pragma unroll
      for (int off = 32; off; off >>= 1) ssum += __shfl_down(ssum, off, 64);
      if (lane == 0) HqS_s = (int)ssum;
    } else {
      while (__hip_atomic_load(&flag, __ATOMIC_ACQUIRE, __HIP_MEMORY_SCOPE_WORKGROUP) < t) { }
    }
    // ---- phase D: dots ----
    const unsigned* hb = &hq[t & 1][part * 28];
    const unsigned* wl = &Wl[tid * 28];
    unsigned a0 = 0, a1 = 0, a2 = 0;
#pragma unroll
    for (int c = 0; c < 6; ++c) {
      uint4 h4 = *(const uint4*)(hb + 4 * c);
      a0 = udot4_(wq[0][4*c+0], h4.x, a0);
      a0 = udot4_(wq[0][4*c+1], h4.y, a0);
      a0 = udot4_(wq[0][4*c+2], h4.z, a0);
      a0 = udot4_(wq[0][4*c+3], h4.w, a0);
      a1 = udot4_(wq[1][4*c+0], h4.x, a1);
      a1 = udot4_(wq[1][4*c+1], h4.y, a1);
      a1 = udot4_(wq[1][4*c+2], h4.z, a1);
      a1 = udot4_(wq[1][4*c+3], h4.w, a1);
      if (tid < 176) {
        uint4 w4 = *(const uint4*)(wl + 4 * c);
        a2 = udot4_(w4.x, h4.x, a2);
        a2 = udot4_(w4.y, h4.y, a2);
        a2 = udot4_(w4.z, h4.z, a2);
        a2 = udot4_(w4.w, h4.w, a2);
      }
    }
    {
      unsigned hl = hb[24];
      a0 = udot4_(wq[0][24], hl, a0);
      a1 = udot4_(wq[1][24], hl, a1);
      if (tid < 176) a2 = udot4_(wl[24], hl, a2);
    }
    a0 += __shfl_xor(a0, 1); a0 += __shfl_xor(a0, 2);
    a1 += __shfl_xor(a1, 1); a1 += __shfl_xor(a1, 2);
    a2 += __shfl_xor(a2, 1); a2 += __shfl_xor(a2, 2);
    if (part == 0)      dots_i[grp]       = (int)a0;
    else if (part == 1) dots_i[128 + grp] = (int)a1;
    else if (part == 2) { if (grp < 44) dots_i[256 + grp] = (int)a2; }
    __syncthreads();   // A: dots + HqS ready

    // ---- phase E: elementwise + repack + publish ----
    if (tid < 75) acew[(t + 1) & 1][tid] = pf;
    if (tid < 100) {
      const int j = tid;   // local j 0..99
      const unsigned char* ab = (const unsigned char*)&acew[t & 1][0];
      float av = ((float)ab[j]       - P.a.z) * P.a.s;
      float cv = ((float)ab[100 + j] - P.c.z) * P.c.s;
      float ev = ((float)ab[200 + j] - P.e.z) * P.e.s;
      int hqs = HqS_s;
      int Ib = dots_i[j]       - zwr * hqs + ic_l[j];
      int Id = dots_i[100 + j] - zwz * hqs + ic_l[100 + j];
      int If = dots_i[200 + j] - zwn * hqs + ic_l[200 + j];
      float bb = fq_((float)Ib * swr, P.b1.s, P.b1.z) + bias_l[j];
      bb = fq_(bb, P.b2.s, P.b2.z);
      float dd = fq_((float)Id * swz, P.d1.s, P.d1.z) + bias_l[100 + j];
      dd = fq_(dd, P.d2.s, P.d2.z);
      float ff = fq_((float)If * swn, P.f1.s, P.f1.z) + bias_l[200 + j];
      ff = fq_(ff, P.f2.s, P.f2.z);
      float r  = fq_(sigm_(fq_(av + bb, P.r1.s, P.r1.z)), P.r2.s, P.r2.z);
      float zz = fq_(sigm_(fq_(cv + dd, P.z1.s, P.z1.z)), P.z2.s, P.z2.z);
      float nn = fq_(tanhf(fq_(ev + fq_(r * ff, P.n1.s, P.n1.z), P.n2.s, P.n2.z)), P.n3.s, P.n3.z);
      float hold = ((float)hcode - P.rnn.z) * P.rnn.s;
      float hn2v = fq_(fq_(1.f - zz, P.hn1.s, P.hn1.z) * nn, P.hn2.s, P.hn2.z);
      float hn3v = fq_(zz * hold, P.hn3.s, P.hn3.z);
      float hnew = hn2v + hn3v;
      float qv = rintf(hnew / P.rnn.s) + P.rnn.z;
      qv = fminf(fmaxf(qv, 0.f), 255.f);
      unsigned code = (unsigned)qv;
      hcode = code;
      unsigned c1 = __shfl_down(code, 1);
      unsigned c2 = __shfl_down(code, 2);
      unsigned c3 = __shfl_down(code, 3);
      if ((j & 3) == 0) {
        unsigned packed = code | (c1 << 8) | (c2 << 16) | (c3 << 24);
        int wrd = j >> 2;                  // 0..24
        hq[(t + 1) & 1][sl * 28 + wrd] = packed;
        *(unsigned*)(hs + ((size_t)t * 64 + b) * 400 + ((sl * 25 + wrd) << 2)) = packed;
        unsigned long long out64 = ((unsigned long long)(unsigned)(t + 1) << 32) | packed;
        unsigned long long* dst = hpub + ((size_t)((t + 1) & 3) * 64 + b) * 100 + sl * 25 + wrd;
        __hip_atomic_store(dst, out64, __ATOMIC_RELAXED, __HIP_MEMORY_SCOPE_AGENT);
      }
    }
    __syncthreads();   // B: h(t+1) own words, ace(t+1) ready
  }
}

// ---------------- host launch ----------------
extern "C" void kernel_launch(void* const* d_in, const int* in_sizes, int n_in,
                              void* d_out, int out_size, void* d_ws, size_t ws_size,
                              hipStream_t stream)
{
  const float* x    = (const float*)d_in[0];
  const float* Wfc1 = (const float*)d_in[1];
  const float* bfc1 = (const float*)d_in[2];
  const float* Wiz1 = (const float*)d_in[3];  const float* Whz1 = (const float*)d_in[4];
  const float* biz1 = (const float*)d_in[5];  const float* bhz1 = (const float*)d_in[6];
  const float* Wir1 = (const float*)d_in[7];  const float* Whr1 = (const float*)d_in[8];
  const float* bir1 = (const float*)d_in[9];  const float* bhr1 = (const float*)d_in[10];
  const float* Win1 = (const float*)d_in[11]; const float* Whn1 = (const float*)d_in[12];
  const float* bin1 = (const float*)d_in[13]; const float* bhn1 = (const float*)d_in[14];
  const float* Wiz2 = (const float*)d_in[15]; const float* Whz2 = (const float*)d_in[16];
  const float* biz2 = (const float*)d_in[17]; const float* bhz2 = (const float*)d_in[18];
  const float* Wir2 = (const float*)d_in[19]; const float* Whr2 = (const float*)d_in[20];
  const float* bir2 = (const float*)d_in[21]; const float* bhr2 = (const float*)d_in[22];
  const float* Win2 = (const float*)d_in[23]; const float* Whn2 = (const float*)d_in[24];
  const float* bin2 = (const float*)d_in[25]; const float* bhn2 = (const float*)d_in[26];
  const float* Wfc2 = (const float*)d_in[27]; const float* bfc2 = (const float*)d_in[28];
  const float* Wfc3 = (const float*)d_in[29]; const float* bfc3 = (const float*)d_in[30];
  const float* Wfc4 = (const float*)d_in[31]; const float* bfc4 = (const float*)d_in[32];
  float* out = (float*)d_out;

  char* wp = (char*)d_ws;
  auto alloc = [&](size_t bytes) -> void* {
    void* p = (void*)wp;
    wp += (bytes + 255) & ~(size_t)255;
    return p;
  };
  float* b1q = (float*)alloc(400 * 4);
  float* biq = (float*)alloc(2400 * 4);
  float* bhq = (float*)alloc(2400 * 4);
  float* b2q = (float*)alloc(600 * 4);
  float* b3q = (float*)alloc(600 * 4);
  float* b4q = (float*)alloc(257 * 4);
  unsigned char* WhC = (unsigned char*)alloc(960000);
  int* colsum = (int*)alloc(2400 * 4);
  signed char* WiT = (signed char*)alloc(7 * 400 * 464);  // 6 proj + W1
  signed char* Bt2 = (signed char*)alloc(600 * 464);      // W2 (i8)
  bf16_t* Bt3 = (bf16_t*)alloc(600 * 608 * 2);            // W3 bf16 codes
  bf16_t* Bt4 = (bf16_t*)alloc(257 * 608 * 2);            // W4 bf16 codes
  int* cwi = (int*)alloc((7 * 400 + 600) * 4);
  int* rsX1 = (int*)alloc(64000 * 4);
  int* rsX  = (int*)alloc(64000 * 4);
  int* rsH  = (int*)alloc(64000 * 4);
  int* rsH2 = (int*)alloc(64000 * 4);
  unsigned char* xsq = (unsigned char*)alloc(25600000);
  unsigned char* Aq  = (unsigned char*)alloc(25600000);
  unsigned char* Cq  = (unsigned char*)alloc(25600000);
  unsigned char* Eq  = (unsigned char*)alloc(25600000);
  unsigned char* hs1 = (unsigned char*)alloc(25600000);
  unsigned char* hs2 = (unsigned char*)alloc(25600000);
  unsigned long long* hpub1 = (unsigned long long*)alloc(25600 * 8);
  unsigned long long* hpub2 = (unsigned long long*)alloc(25600 * 8);
  // overlays on dead regions
  float* y2c = (float*)Aq;                       // 38.4 MB (A/C/E dead during FC chain)
  float* y3c = (float*)(Aq + 38400000);          // 38.4 MB
  unsigned char* xcq = hs1;                      // x codes [64000][464] (hs1 dead pre-rec1)

  // ---- merged prep: all 16 bias fq in one launch ----
  BJobs bj;
  bj.j[0]  = { bfc1, b1q,        400, Zbfc1.s, Zbfc1.z };
  bj.j[1]  = { bir1, biq + 0,    400, Zbir1.s, Zbir1.z };
  bj.j[2]  = { biz1, biq + 400,  400, Zbiz1.s, Zbiz1.z };
  bj.j[3]  = { bin1, biq + 800,  400, Zbin1.s, Zbin1.z };
  bj.j[4]  = { bir2, biq + 1200, 400, Zbir2.s, Zbir2.z };
  bj.j[5]  = { biz2, biq + 1600, 400, Zbiz2.s, Zbiz2.z };
  bj.j[6]  = { bin2, biq + 2000, 400, Zbin2.s, Zbin2.z };
  bj.j[7]  = { bhr1, bhq + 0,    400, Zbhr1.s, Zbhr1.z };
  bj.j[8]  = { bhz1, bhq + 400,  400, Zbhz1.s, Zbhz1.z };
  bj.j[9]  = { bhn1, bhq + 800,  400, Zbhn1.s, Zbhn1.z };
  bj.j[10] = { bhr2, bhq + 1200, 400, Zbhr2.s, Zbhr2.z };
  bj.j[11] = { bhz2, bhq + 1600, 400, Zbhz2.s, Zbhz2.z };
  bj.j[12] = { bhn2, bhq + 2000, 400, Zbhn2.s, Zbhn2.z };
  bj.j[13] = { bfc2, b2q,        600, Zbfc2.s, Zbfc2.z };
  bj.j[14] = { bfc3, b3q,        600, Zbfc3.s, Zbfc3.z };
  bj.j[15] = { bfc4, b4q,        257, Zbfc4.s, Zbfc4.z };
  kbias<<<dim3(16), dim3(256), 0, stream>>>(bj);

  W6 wh = { { Whr1, Whz1, Whn1, Whr2, Whz2, Whn2 },
            { ZWhr1.s, ZWhz1.s, ZWhn1.s, ZWhr2.s, ZWhz2.s, ZWhn2.s },
            { ZWhr1.z, ZWhz1.z, ZWhn1.z, ZWhr2.z, ZWhz2.z, ZWhn2.z } };
  kwhc6<<<dim3(3750), dim3(256), 0, stream>>>(wh, WhC);
  kcolsum<<<dim3(10), dim3(256), 0, stream>>>(WhC, colsum);
  unsigned code0 = (unsigned)(Zrnn.z < 0.f ? 0.f : (Zrnn.z > 255.f ? 255.f : Zrnn.z));
  kinit2<<<dim3(100), dim3(256), 0, stream>>>(hpub1, hpub2, code0);

  hipMemsetAsync(cwi, 0, (7 * 400 + 600) * 4, stream);
  W6 wi = { { Wir1, Wiz1, Win1, Wir2, Wiz2, Win2 },
            { ZWir1.s, ZWiz1.s, ZWin1.s, ZWir2.s, ZWiz2.s, ZWin2.s },
            { ZWir1.z, ZWiz1.z, ZWin1.z, ZWir2.z, ZWiz2.z, ZWin2.z } };
  kwic6<<<dim3(625), dim3(256), 0, stream>>>(wi, WiT, cwi);
  kwic<<<dim3(625), dim3(256), 0, stream>>>(Wfc1, WiT + (size_t)6 * 185600, cwi + 2400, ZW1.s, ZW1.z, 257, 400);
  kwic<<<dim3(625), dim3(256), 0, stream>>>(Wfc2, Bt2, cwi + 2800, ZWfc2.s, ZWfc2.z, 400, 600);
  kwbf<<<dim3(625), dim3(256), 0, stream>>>(Wfc3, Bt3, ZWfc3.s, ZWfc3.z, 600, 600);
  kwbf<<<dim3(625), dim3(256), 0, stream>>>(Wfc4, Bt4, ZWfc4.s, ZWfc4.z, 600, 257);

  auto gi8 = [&](const unsigned char* A, int strideA, int aw4, const int* rs,
                 const signed char* Bt, const int* cs, const float* bias,
                 unsigned char* oU8, float* oF, int M, int N, int outStride, int epMode,
                 SZ a, SZ w, int Kreal, float ss, SZ e1, SZ e2) {
    int czw = 128 - (int)w.z, cza = 128 - (int)a.z;
    int cconst = Kreal * cza * czw;
    int nb = (N + 79) / 80;
    gemm_i8<<<dim3((M / 64) * nb), dim3(256), 0, stream>>>(
        A, strideA, aw4, rs, Bt, cs, bias, oU8, oF, N, nb, outStride, epMode,
        czw, cza, cconst, ss, e1.s, e1.z, e2.s, e2.z);
  };

  // ---- FC1 (exact-int i8): x codes -> xsq codes ----
  kxq<<<dim3((64000 * 464 + 255) / 256), dim3(256), 0, stream>>>(x, xcq, Zx.s, Zx.z);
  krsum<<<dim3(250), dim3(256), 0, stream>>>(xcq, rsX1, 29);
  gi8(xcq, 464, 29, rsX1, WiT + (size_t)6 * 185600, cwi + 2400, b1q,
      xsq, nullptr, 64000, 400, 400, 0, Zx, ZW1, 257, Zx.s * ZW1.s, Zfc1mm, Zfc1add);

  // ---- GRU layer 1 input projections (i8) ----
  krsum<<<dim3(250), dim3(256), 0, stream>>>(xsq, rsX, 25);
  gi8(xsq, 400, 25, rsX, WiT + (size_t)0 * 185600, cwi + 0,    biq + 0,   Aq, nullptr,
      64000, 400, 400, 0, Zfc1add, ZWir1, 400, Zfc1add.s * ZWir1.s, Za_1, Za1);
  gi8(xsq, 400, 25, rsX, WiT + (size_t)1 * 185600, cwi + 400,  biq + 400, Cq, nullptr,
      64000, 400, 400, 0, Zfc1add, ZWiz1, 400, Zfc1add.s * ZWiz1.s, Zc_1, Zc1);
  gi8(xsq, 400, 25, rsX, WiT + (size_t)2 * 185600, cwi + 800,  biq + 800, Eq, nullptr,
      64000, 400, 400, 0, Zfc1add, ZWin1, 400, Zfc1add.s * ZWin1.s, Ze_1, Ze1);
  // ---- GRU layer 1 recurrence (4 blocks per batch) ----
  gru_rec4b<<<dim3(256), dim3(512), 0, stream>>>(WhC, colsum, Aq, Cq, Eq,
                                                 bhq + 0, bhq + 400, bhq + 800,
                                                 hs1, hpub1, PL1);
  // ---- GRU layer 2 input projections (i8) ----
  krsum<<<dim3(250), dim3(256), 0, stream>>>(hs1, rsH, 25);
  gi8(hs1, 400, 25, rsH, WiT + (size_t)3 * 185600, cwi + 1200, biq + 1200, Aq, nullptr,
      64000, 400, 400, 0, Zrnn, ZWir2, 400, Zrnn.s * ZWir2.s, Za_2, Za2);
  gi8(hs1, 400, 25, rsH, WiT + (size_t)4 * 185600, cwi + 1600, biq + 1600, Cq, nullptr,
      64000, 400, 400, 0, Zrnn, ZWiz2, 400, Zrnn.s * ZWiz2.s, Zc_2, Zc2);
  gi8(hs1, 400, 25, rsH, WiT + (size_t)5 * 185600, cwi + 2000, biq + 2000, Eq, nullptr,
      64000, 400, 400, 0, Zrnn, ZWin2, 400, Zrnn.s * ZWin2.s, Ze_2, Ze1);
  // ---- GRU layer 2 recurrence ----
  gru_rec4b<<<dim3(256), dim3(512), 0, stream>>>(WhC + 480000, colsum + 1200, Aq, Cq, Eq,
                                                 bhq + 1200, bhq + 1600, bhq + 2000,
                                                 hs2, hpub2, PL2);
  // ---- FC2 (i8) -> FC3 -> FC4 (bf16x2 MFMA) in 4 row chunks ----
  krsum<<<dim3(250), dim3(256), 0, stream>>>(hs2, rsH2, 25);
  for (int rc = 0; rc < 4; ++rc) {
    const unsigned char* a2 = hs2 + (size_t)rc * 16000 * 400;
    gi8(a2, 400, 25, rsH2 + rc * 16000, Bt2, cwi + 2800, b2q, nullptr, y2c,
        16000, 600, 600, 2, Zrnn, ZWfc2, 400, Zrnn.s * ZWfc2.s, Zrnn, Zrnn);
    gemm_bf<<<dim3(125 * 5), dim3(512), 0, stream>>>(y2c, Bt3, b3q, y3c, 600, 5, 2, 0, ZWfc3.s);
    gemm_bf<<<dim3(125 * 3), dim3(512), 0, stream>>>(y3c, Bt4, b4q, out, 257, 3, 3, rc * 16000, ZWfc4.s);
  }
  (void)in_sizes; (void)n_in; (void)out_size; (void)ws_size;
}